// Round 6
// baseline (885.815 us; speedup 1.0000x reference)
//
#include <hip/hip_runtime.h>

typedef unsigned short u16;
typedef unsigned int u32;

using short8 = __attribute__((ext_vector_type(8))) short;
using s4     = __attribute__((ext_vector_type(4))) short;
using f32x4  = __attribute__((ext_vector_type(4))) float;

constexpr int kB = 2, kT = 2048, kD = 2048, kH = 16, kK = 128, kV = 128;
constexpr int kM  = kB * kT;   // 4096 tokens
constexpr int kHK = kH * kK;   // 2048
constexpr int kHV = kH * kV;   // 2048
constexpr int CC  = 16;        // scan chunk length
constexpr int NCH = kT / CC;   // 128 chunks

// ---------------- workspace layout (bytes). Overlays are deliberate. -------
constexpr size_t OFF_XB    = 0;          // bf16 x [4096][2048] (dead after gemms)
constexpr size_t OFF_WQKV  = 16777216;   // bf16 [6144][2048] = Wq|Wk|Wv stacked
constexpr size_t OFF_QC    = 0;          // f32 qc [32][2048][128] (convprep out)
constexpr size_t OFF_YF    = 0;          // f32 y (p2 out; qc dead after p1)
constexpr size_t OFF_WF1B  = 41943040;   // bf16 Wf1 [128][2048]
constexpr size_t OFF_WG1B  = 42467328;   // bf16 Wg1
constexpr size_t OFF_WBP   = 42991616;   // bf16 Wb padded [128][2048]
constexpr size_t OFF_WF2B  = 43515904;   // bf16 Wf2
constexpr size_t OFF_WG2B  = 44040192;   // bf16 Wg2
constexpr size_t OFF_FGB   = 44564480;   // bf16 fgb [4096][384] (f1|g1|braw)
constexpr size_t OFF_QKVR  = 48758784;   // bf16 qkvraw [4096][6144]
constexpr size_t OFF_QHB   = 48758784;   // bf16 qhat [32][2048][128] (over qkvraw)
constexpr size_t OFF_KBB   = 65536000;   // bf16 kbar TRANSPOSED [32][128ch][128k][16t]
constexpr size_t OFF_KHB   = 82313216;   // bf16 khat
constexpr size_t OFF_YGB   = 82313216;   // bf16 y-gated (postk out, khb dead by then)
constexpr size_t OFF_GRAW  = 99090432;   // bf16 g_raw (dead after convprep)
constexpr size_t OFF_LAM   = 99090432;   // f32 lam  [32][128][128] (over graw)
constexpr size_t OFF_WINV  = 101187584;  // bf16 winv hi [32][128][16][16] | lo at +2MB
constexpr size_t OFF_MM    = 105381888;  // bf16 M hi | lo at +2MB
constexpr size_t OFF_GATEB = 115867648;  // bf16 gate [4096][2048]
constexpr size_t OFF_WOUTB = 132644864;  // bf16 Wout
constexpr size_t OFF_KC    = 141033472;  // f32 kc
constexpr size_t OFF_VT    = 174587904;  // f32 v transposed [bh*8+vs][t][16]
constexpr size_t OFF_GK    = 208142336;  // f32 log-decay g
constexpr size_t OFF_BETA  = 241696768;  // f32 beta [32][2048]
// total 241958912 bytes (~231 MB), unchanged

// ---------------- small helpers ----------------
__device__ __forceinline__ u16 f2bf(float f) {
  union { float f; u32 u; } a; a.f = f;
  u32 u = a.u;
  u += 0x7fffu + ((u >> 16) & 1u);   // round-to-nearest-even
  return (u16)(u >> 16);
}
__device__ __forceinline__ float bflo(u32 u) {
  union { u32 u; float f; } a; a.u = u << 16; return a.f;
}
__device__ __forceinline__ float bfhi(u32 u) {
  union { u32 u; float f; } a; a.u = u & 0xffff0000u; return a.f;
}
union BU { uint2 u; s4 s; };
__device__ __forceinline__ s4 us(uint2 u) { BU x; x.u = u; return x.s; }
// fast sigmoid: v_exp + v_rcp (~1 ulp each; all consumers round to bf16)
__device__ __forceinline__ float sigmoidf(float x) {
  return __builtin_amdgcn_rcpf(1.0f + __expf(-x));
}
// 16x16x16 bf16 MFMA. Fragment layouts:
// A: row=lane&15, k=(lane>>4)*4+i ; B: k=(lane>>4)*4+i, col=lane&15 ;
// C/D: row=(lane>>4)*4+r, col=lane&15  -> D layout == B layout (chainable).
__device__ __forceinline__ f32x4 mfma16b(s4 a, s4 b, f32x4 c) {
  return __builtin_amdgcn_mfma_f32_16x16x16bf16_1k(a, b, c, 0, 0, 0);
}
// pack f32x4 (D-frag) into bf16 hi + lo uint2 pair (unscaled; bf16 keeps the
// f32 exponent range so lo parts never denormalize)
__device__ __forceinline__ void packhl(const f32x4& v, uint2& hw, uint2& lw) {
  u16 h0 = f2bf(v[0]), h1 = f2bf(v[1]), h2 = f2bf(v[2]), h3 = f2bf(v[3]);
  hw.x = (u32)h0 | ((u32)h1 << 16); hw.y = (u32)h2 | ((u32)h3 << 16);
  lw.x = (u32)f2bf(v[0] - bflo(h0)) | ((u32)f2bf(v[1] - bflo(h1)) << 16);
  lw.y = (u32)f2bf(v[2] - bflo(h2)) | ((u32)f2bf(v[3] - bflo(h3)) << 16);
}

#define GL_AS1 __attribute__((address_space(1)))
#define GL_AS3 __attribute__((address_space(3)))
__device__ __forceinline__ void async_lds16(const void* g, void* l) {
  __builtin_amdgcn_global_load_lds((GL_AS1 u32*)(size_t)g,
                                   (GL_AS3 u32*)(u32)(size_t)l, 16, 0, 0);
}

// ---------------- fused cast of all f32->bf16 weights/x --------------------
__global__ __launch_bounds__(256) void cast_all(
    const float* __restrict__ x, const float* __restrict__ Wq,
    const float* __restrict__ Wk, const float* __restrict__ Wv,
    const float* __restrict__ Wout, const float* __restrict__ Wf1,
    const float* __restrict__ Wg1, const float* __restrict__ Wf2,
    const float* __restrict__ Wg2,
    u16* __restrict__ xb, u16* __restrict__ wqkv, u16* __restrict__ woutb,
    u16* __restrict__ wf1b, u16* __restrict__ wg1b, u16* __restrict__ wf2b,
    u16* __restrict__ wg2b) {
  long qi = (long)blockIdx.x * 256 + threadIdx.x;   // float4 index
  const float* src; u16* dst; long off;
  if (qi < 2097152)      { src = x;    dst = xb;             off = qi; }
  else if (qi < 3145728) { src = Wq;   dst = wqkv;           off = qi - 2097152; }
  else if (qi < 4194304) { src = Wk;   dst = wqkv + 4194304; off = qi - 3145728; }
  else if (qi < 5242880) { src = Wv;   dst = wqkv + 8388608; off = qi - 4194304; }
  else if (qi < 6291456) { src = Wout; dst = woutb;          off = qi - 5242880; }
  else if (qi < 6356992) { src = Wf1;  dst = wf1b;           off = qi - 6291456; }
  else if (qi < 6422528) { src = Wg1;  dst = wg1b;           off = qi - 6356992; }
  else if (qi < 6488064) { src = Wf2;  dst = wf2b;           off = qi - 6422528; }
  else                   { src = Wg2;  dst = wg2b;           off = qi - 6488064; }
  long i = off * 4;
  float4 v = *(const float4*)(src + i);
  uint2 st;
  st.x = (u32)f2bf(v.x) | ((u32)f2bf(v.y) << 16);
  st.y = (u32)f2bf(v.z) | ((u32)f2bf(v.w) << 16);
  *(uint2*)(dst + i) = st;
}

// Wb [16,2048] f32 -> [128,2048] bf16 zero-padded
__global__ __launch_bounds__(256) void pad_wb(const float* __restrict__ Wb,
                                              u16* __restrict__ out) {
  int i = (blockIdx.x * 256 + threadIdx.x) * 4;  // < 262144
  int row = i >> 11;
  uint2 st; st.x = 0; st.y = 0;
  if (row < 16) {
    float4 v = *(const float4*)(Wb + i);
    st.x = (u32)f2bf(v.x) | ((u32)f2bf(v.y) << 16);
    st.y = (u32)f2bf(v.z) | ((u32)f2bf(v.w) << 16);
  }
  *(uint2*)(out + i) = st;
}

// ---------------- bf16 MFMA GEMM:  C[m,n] = sum_k A[m,k] * B[n,k] ----------
template <bool BF16OUT>
__global__ __launch_bounds__(256) void gemm_bt(const u16* __restrict__ A,
                                               const u16* __restrict__ B,
                                               void* __restrict__ Cout,
                                               int lda, int ldb, int ldc, int K) {
  __shared__ u16 As[128 * 32];
  __shared__ u16 Bs[128 * 32];
  const int tid  = threadIdx.x;
  const int lane = tid & 63;
  const int wave = tid >> 6;
  const int wm = (wave >> 1) * 64;
  const int wn = (wave & 1) * 64;
  const long row0 = (long)blockIdx.x * 128;
  const long col0 = (long)blockIdx.y * 128;
  const int srow = tid >> 2;
  const int scol = (tid & 3) * 8;
  const u16* aptr = A + (row0 + srow) * (size_t)lda + scol;
  const u16* bptr = B + (col0 + srow) * (size_t)ldb + scol;
  u16* asd  = &As[tid * 8];
  u16* asd2 = &As[2048 + tid * 8];
  u16* bsd  = &Bs[tid * 8];
  u16* bsd2 = &Bs[2048 + tid * 8];
  const int mrow = lane & 15;
  const int kq = (lane >> 4) * 8;
  f32x4 acc[4][4] = {};
  for (int k0 = 0; k0 < K; k0 += 32) {
    async_lds16(aptr, asd);
    async_lds16(aptr + (size_t)64 * lda, asd2);
    async_lds16(bptr, bsd);
    async_lds16(bptr + (size_t)64 * ldb, bsd2);
    aptr += 32; bptr += 32;
    __syncthreads();
    short8 af[4], bfr[4];
#pragma unroll
    for (int i = 0; i < 4; ++i)
      af[i] = *(const short8*)(&As[(wm + i * 16 + mrow) * 32 + kq]);
#pragma unroll
    for (int j = 0; j < 4; ++j)
      bfr[j] = *(const short8*)(&Bs[(wn + j * 16 + mrow) * 32 + kq]);
#pragma unroll
    for (int i = 0; i < 4; ++i)
#pragma unroll
      for (int j = 0; j < 4; ++j)
        acc[i][j] = __builtin_amdgcn_mfma_f32_16x16x32_bf16(af[i], bfr[j], acc[i][j], 0, 0, 0);
    __syncthreads();
  }
  const int cn = lane & 15;
  const int rq = (lane >> 4) * 4;
#pragma unroll
  for (int i = 0; i < 4; ++i)
#pragma unroll
    for (int j = 0; j < 4; ++j) {
      size_t r = (size_t)(row0 + wm + i * 16 + rq);
      size_t c = (size_t)(col0 + wn + j * 16 + cn);
#pragma unroll
      for (int rr = 0; rr < 4; ++rr) {
        if constexpr (BF16OUT)
          ((u16*)Cout)[(r + rr) * ldc + c] = f2bf(acc[i][j][rr]);
        else
          ((float*)Cout)[(r + rr) * ldc + c] = acc[i][j][rr];
      }
    }
}

// ---------------- conv(4-tap causal) + silu + l2norm + g + beta ------------
__global__ __launch_bounds__(256) void convprep(
    const u16* __restrict__ qkv, const u16* __restrict__ graw,
    const u16* __restrict__ fgb,
    const float* __restrict__ qcw, const float* __restrict__ kcw,
    const float* __restrict__ vcw, const float* __restrict__ A_log,
    const float* __restrict__ dt_bias,
    float* __restrict__ qc, float* __restrict__ kc, float* __restrict__ vt,
    float* __restrict__ gdec, float* __restrict__ beta) {
  const int wid = blockIdx.x * 8 + (threadIdx.x >> 5);  // (b*T+t)*H + h
  const int l32 = threadIdx.x & 31;
  const int h  = wid & 15;
  const int bt = wid >> 4;        // b*T + t
  const int t  = bt & (kT - 1);
  const int b  = bt >> 11;
  const int c0 = l32 * 4;
  const size_t colofs = (size_t)h * kK + c0;
  const size_t rowb = (size_t)bt * 6144 + colofs;
  float wqt[4][4], wkt[4][4], wvt[4][4];
#pragma unroll
  for (int j = 0; j < 4; ++j) {
    *(float4*)wqt[j] = *(const float4*)(qcw + (colofs + j) * 4);
    *(float4*)wkt[j] = *(const float4*)(kcw + (colofs + j) * 4);
    *(float4*)wvt[j] = *(const float4*)(vcw + (colofs + j) * 4);
  }
  float qa[4] = {0.f, 0.f, 0.f, 0.f};
  float ka[4] = {0.f, 0.f, 0.f, 0.f};
  float va[4] = {0.f, 0.f, 0.f, 0.f};
#pragma unroll
  for (int i = 0; i < 4; ++i) {
    int tt = t - 3 + i;
    if (tt >= 0) {   // wave-uniform branch
      size_t ro = rowb - (size_t)(3 - i) * 6144;
      uint2 uq = *(const uint2*)(qkv + ro);
      uint2 uk = *(const uint2*)(qkv + ro + 2048);
      uint2 uv = *(const uint2*)(qkv + ro + 4096);
      float q0 = bflo(uq.x), q1 = bfhi(uq.x), q2 = bflo(uq.y), q3 = bfhi(uq.y);
      float k0 = bflo(uk.x), k1 = bfhi(uk.x), k2 = bflo(uk.y), k3 = bfhi(uk.y);
      float v0 = bflo(uv.x), v1 = bfhi(uv.x), v2 = bflo(uv.y), v3 = bfhi(uv.y);
      qa[0] = fmaf(q0, wqt[0][i], qa[0]); qa[1] = fmaf(q1, wqt[1][i], qa[1]);
      qa[2] = fmaf(q2, wqt[2][i], qa[2]); qa[3] = fmaf(q3, wqt[3][i], qa[3]);
      ka[0] = fmaf(k0, wkt[0][i], ka[0]); ka[1] = fmaf(k1, wkt[1][i], ka[1]);
      ka[2] = fmaf(k2, wkt[2][i], ka[2]); ka[3] = fmaf(k3, wkt[3][i], ka[3]);
      va[0] = fmaf(v0, wvt[0][i], va[0]); va[1] = fmaf(v1, wvt[1][i], va[1]);
      va[2] = fmaf(v2, wvt[2][i], va[2]); va[3] = fmaf(v3, wvt[3][i], va[3]);
    }
  }
  float sq = 0.f, sk = 0.f;
#pragma unroll
  for (int j = 0; j < 4; ++j) {
    qa[j] *= sigmoidf(qa[j]);            // silu
    ka[j] *= sigmoidf(ka[j]);
    va[j] *= sigmoidf(va[j]);
    sq = fmaf(qa[j], qa[j], sq);
    sk = fmaf(ka[j], ka[j], sk);
  }
#pragma unroll
  for (int m = 1; m < 32; m <<= 1) {     // reduce within the 32-lane row
    sq += __shfl_xor(sq, m);
    sk += __shfl_xor(sk, m);
  }
  float qinv = __builtin_amdgcn_rcpf(fmaxf(__builtin_amdgcn_sqrtf(sq), 1e-12f));
  float kinv = __builtin_amdgcn_rcpf(fmaxf(__builtin_amdgcn_sqrtf(sk), 1e-12f));
  const int bh = b * kH + h;
  const size_t outb = ((size_t)bh * kT + t) * kK + c0;
  *(float4*)(qc + outb) =
      make_float4(qa[0] * qinv, qa[1] * qinv, qa[2] * qinv, qa[3] * qinv);
  *(float4*)(kc + outb) =
      make_float4(ka[0] * kinv, ka[1] * kinv, ka[2] * kinv, ka[3] * kinv);
  const size_t vtb = ((size_t)(bh * 8 + (c0 >> 4)) * kT + t) * 16 + (c0 & 15);
  *(float4*)(vt + vtb) = make_float4(va[0], va[1], va[2], va[3]);
  uint2 ug = *(const uint2*)(graw + (size_t)bt * kHK + colofs);
  float Ae = __expf(A_log[h]);
  float4 db = *(const float4*)(dt_bias + colofs);
  float g0 = bflo(ug.x) + db.x;
  float g1 = bfhi(ug.x) + db.y;
  float g2 = bflo(ug.y) + db.z;
  float g3 = bfhi(ug.y) + db.w;
  float sp0 = (g0 > 15.f) ? g0 : __logf(1.f + __expf(g0));
  float sp1 = (g1 > 15.f) ? g1 : __logf(1.f + __expf(g1));
  float sp2 = (g2 > 15.f) ? g2 : __logf(1.f + __expf(g2));
  float sp3 = (g3 > 15.f) ? g3 : __logf(1.f + __expf(g3));
  *(float4*)(gdec + outb) = make_float4(-Ae * sp0, -Ae * sp1, -Ae * sp2, -Ae * sp3);
  if (l32 == 0) {
    float bv = bflo((u32)fgb[(size_t)bt * 384 + 256 + h]);
    beta[(size_t)bh * kT + t] = sigmoidf(bv);
  }
}

// ---------------- KDA pass 1: per (bh,chunk) transforms --------------------
// Emits BF16 khat=k*e^G, qhat=q*e^G (layout [t][k]); kbar=k*e^{GC-G} written
// TRANSPOSED per chunk ([k][16 t]). f32 lam=e^{GC}. Winv=(I+B trilA)^{-1}B
// and M emitted as BF16 hi+lo pairs. Everything built from the bf16-ROUNDED
// khat/qhat/kbar so the chunk algebra is exactly consistent with p2's bf16
// MFMA operands.
__global__ __launch_bounds__(256) void kda_p1(
    const float* __restrict__ qc, const float* __restrict__ kc,
    const float* __restrict__ gk, const float* __restrict__ betap,
    u16* __restrict__ qhb, u16* __restrict__ khb, u16* __restrict__ kbt,
    float* __restrict__ lamC, u16* __restrict__ whv, u16* __restrict__ wlv,
    u16* __restrict__ mhv, u16* __restrict__ mlv) {
  __shared__ float kL[CC][132], qL[CC][132], gL[CC][132];
  __shared__ float As[CC][CC], Ms[CC][CC];
  __shared__ float bet[CC];
  const int tid = threadIdx.x;
  const int bh = blockIdx.x >> 7;
  const int ch = blockIdx.x & 127;
  const size_t base = ((size_t)bh * kT + ch * CC) * kK;
  const int e = tid * 8;
  const int t = e >> 7, k = e & 127;
  {
    *(float4*)&kL[t][k]     = *(const float4*)(kc + base + e);
    *(float4*)&kL[t][k + 4] = *(const float4*)(kc + base + e + 4);
    *(float4*)&qL[t][k]     = *(const float4*)(qc + base + e);
    *(float4*)&qL[t][k + 4] = *(const float4*)(qc + base + e + 4);
    *(float4*)&gL[t][k]     = *(const float4*)(gk + base + e);
    *(float4*)&gL[t][k + 4] = *(const float4*)(gk + base + e + 4);
    if (tid < CC) bet[tid] = betap[(size_t)bh * kT + ch * CC + tid];
  }
  __syncthreads();
  if (tid < kK) {        // inclusive cumsum of g over t -> G
    float a = gL[0][tid];
#pragma unroll
    for (int tt = 1; tt < CC; ++tt) { a += gL[tt][tid]; gL[tt][tid] = a; }
  }
  __syncthreads();
  float khr[8], qhr[8], kbw[8];
  u16 kbv[8];
  u32 pk[4] = {0,0,0,0}, pq[4] = {0,0,0,0};
#pragma unroll
  for (int j = 0; j < 8; ++j) {
    float G  = gL[t][k + j];
    float GC = gL[CC - 1][k + j];
    float eg = __expf(G);
    float kh = kL[t][k + j] * eg;
    float qh = qL[t][k + j] * eg;
    float kb = kL[t][k + j] * __expf(GC - G);
    u16 a = f2bf(kh), b_ = f2bf(qh), c = f2bf(kb);
    pk[j >> 1] |= ((u32)a)  << (16 * (j & 1));
    pq[j >> 1] |= ((u32)b_) << (16 * (j & 1));
    kbv[j] = c;
    khr[j] = bflo((u32)a);
    qhr[j] = bflo((u32)b_);
    kbw[j] = bflo((u32)c) * __expf(-GC);   // kbar * e^{-GC} (bf16: no underflow)
  }
  *(uint4*)(khb + base + e) = *(uint4*)pk;
  *(uint4*)(qhb + base + e) = *(uint4*)pq;
  {  // transposed kbar: [bh][ch][k][16 t]
    const size_t kb2 = ((size_t)bh * NCH + ch) * (size_t)(kK * CC) +
                       (size_t)k * CC + t;
#pragma unroll
    for (int j = 0; j < 8; ++j) kbt[kb2 + (size_t)j * CC] = kbv[j];
  }
  if (tid < kK)
    lamC[((size_t)bh * NCH + ch) * kK + tid] = __expf(gL[CC - 1][tid]);
  __syncthreads();   // all GC reads done before overwrite
#pragma unroll
  for (int j = 0; j < 8; ++j) {
    kL[t][k + j] = khr[j];
    qL[t][k + j] = qhr[j];
    gL[t][k + j] = kbw[j];
  }
  __syncthreads();
  {  // A[t][s]=khat_t . (kbar_s e^{-GC}); M[t][s]=qhat_t . (kbar_s e^{-GC})
    const int t2 = tid >> 4, s = tid & 15;
    float av = 0.f, mv = 0.f;
    for (int kk = 0; kk < kK; ++kk) {
      float w = gL[s][kk];
      av = fmaf(kL[t2][kk], w, av);
      mv = fmaf(qL[t2][kk], w, mv);
    }
    As[t2][s] = (s < t2)  ? av : 0.f;
    Ms[t2][s] = (s <= t2) ? mv : 0.f;
  }
  __syncthreads();
  const size_t smb = ((size_t)bh * NCH + ch) * 256;
  if (tid < CC) {  // X = (I + B trilA)^{-1} B, column s -> bf16 hi+lo
    const int s = tid;
    float x[CC];
#pragma unroll
    for (int tt = 0; tt < CC; ++tt) {
      float sum = 0.f;
      for (int r = 0; r < tt; ++r) sum += As[tt][r] * x[r];
      x[tt] = ((tt == s) ? bet[tt] : 0.f) - bet[tt] * sum;
    }
#pragma unroll
    for (int tt = 0; tt < CC; ++tt) {
      u16 xh = f2bf(x[tt]);
      whv[smb + tt * 16 + s] = xh;
      wlv[smb + tt * 16 + s] = f2bf(x[tt] - bflo((u32)xh));
    }
  }
  {
    float mvv = Ms[tid >> 4][tid & 15];
    u16 mhh = f2bf(mvv);
    mhv[smb + tid] = mhh;
    mlv[smb + tid] = f2bf(mvv - bflo((u32)mhh));
  }
}

// ---------------- KDA pass 2: single-wave MFMA chunk recurrence ------------
// 256 blocks = 32 bh x 8 v-slices(16 cols), ONE 64-lane wave per block.
// Full 128x16 state lives in 8 f32 MFMA accumulators + bf16 hi/lo B-frags.
// Zero LDS, zero __syncthreads. This revision adds a STRUCTURAL register
// software-pipeline: all data needed early/mid chunk (khat,qhat,V,Winv,M) is
// double-buffered and loaded ONE CHUNK AHEAD into named registers; kb/lam
// (consumed at chunk end) are issued at the top of the same chunk. This
// forces the loads to overlap compute -- R5's single-buffer version left the
// wave 85% stalled on serialized load->use chains (1 wave/SIMD = no TLP).
// Phase A uses separate hi/lo accumulators: 8 independent 4-deep MFMA chains.
//   P = Khat S ; T1 = V - P ; U = Winv T1 ; O = Qhat S + M U
//   S = lam (.) S + KbarT U
__global__ __launch_bounds__(64, 1) void kda_p2(
    const u16* __restrict__ khb, const u16* __restrict__ qhb,
    const u16* __restrict__ kbt, const float* __restrict__ lamC,
    const u16* __restrict__ whg, const u16* __restrict__ wlg,
    const u16* __restrict__ mhg, const u16* __restrict__ mlg,
    const float* __restrict__ vt, float* __restrict__ yf) {
  const int lane = threadIdx.x;
  const int m15 = lane & 15, q = lane >> 4;
  const int blk = blockIdx.x;
  const int bh = blk & 31, vs = blk >> 5;   // vs-major: all slices of a bh on one XCD
  const u16*  khp  = khb + (size_t)bh * (kT * kK) + (size_t)m15 * kK + 4 * q;
  const u16*  qhp  = qhb + (size_t)bh * (kT * kK) + (size_t)m15 * kK + 4 * q;
  const u16*  kbp  = kbt + (size_t)bh * (NCH * kK * CC) + (size_t)m15 * CC + 4 * q;
  const float* lamp = lamC + (size_t)bh * (NCH * kK) + 4 * q;
  const size_t smb  = (size_t)bh * (NCH * 256) + (size_t)m15 * 16 + 4 * q;
  const float* vp  = vt + ((size_t)(bh * 8 + vs) * kT + 4 * q) * 16 + m15;
  float*       yp  = yf + ((size_t)bh * kT + 4 * q) * kV + vs * 16 + m15;

  f32x4 S[8] = {};              // state acc tiles, k in [16j,16j+16), col v
  uint2 Sh[8] = {}, Sl[8] = {}; // state as bf16 hi/lo B-frags

  uint2 khA[8], qhA[8]; float vA[4]; uint2 whA, wlA, mhA, mlA;
  uint2 khB[8], qhB[8]; float vB[4]; uint2 whB, wlB, mhB, mlB;

#define LKQ(KH, QH, VV, WH, WL, MH, ML, ch) {                                  \
    const u16* k_ = khp + (size_t)(ch) * (CC * kK);                            \
    const u16* q_ = qhp + (size_t)(ch) * (CC * kK);                            \
    _Pragma("unroll") for (int j = 0; j < 8; ++j) {                            \
      KH[j] = *(const uint2*)(k_ + 16 * j);                                    \
      QH[j] = *(const uint2*)(q_ + 16 * j);                                    \
    }                                                                          \
    const float* v_ = vp + (size_t)(ch) * (CC * 16);                           \
    _Pragma("unroll") for (int r = 0; r < 4; ++r) VV[r] = v_[16 * r];          \
    const size_t sm_ = smb + (size_t)(ch) * 256;                               \
    WH = *(const uint2*)(whg + sm_);                                           \
    WL = *(const uint2*)(wlg + sm_);                                           \
    MH = *(const uint2*)(mhg + sm_);                                           \
    ML = *(const uint2*)(mlg + sm_);                                           \
  }

#define CHUNK(KH, QH, VV, WH, WL, MH, ML,                                      \
              KH2, QH2, VV2, WH2, WL2, MH2, ML2, ch) {                         \
    /* prefetch next chunk's early/mid data into the other buffer set */       \
    const int chn_ = ((ch) + 1 < NCH) ? (ch) + 1 : (ch);                       \
    LKQ(KH2, QH2, VV2, WH2, WL2, MH2, ML2, chn_);                              \
    /* in-chunk prefetch: kb/lam consumed at the END of this chunk */          \
    uint2 kb_[8]; float4 lam_[8];                                              \
    const u16* kb0 = kbp + (size_t)(ch) * (kK * CC);                           \
    _Pragma("unroll") for (int j = 0; j < 8; ++j)                              \
      kb_[j] = *(const uint2*)(kb0 + 16 * j * CC);                             \
    const float* l0 = lamp + (size_t)(ch) * kK;                                \
    _Pragma("unroll") for (int j = 0; j < 8; ++j)                              \
      lam_[j] = *(const float4*)(l0 + 16 * j);                                 \
    /* phase A: P = Khat S, Qp = Qhat S -- 8 independent 4-deep chains */      \
    f32x4 z_ = {0.f, 0.f, 0.f, 0.f};                                           \
    f32x4 P0h = z_, P0l = z_, P1h = z_, P1l = z_;                              \
    f32x4 Q0h = z_, Q0l = z_, Q1h = z_, Q1l = z_;                              \
    _Pragma("unroll") for (int j = 0; j < 4; ++j) {                            \
      P0h = mfma16b(us(KH[j]), us(Sh[j]), P0h);                                \
      P1h = mfma16b(us(KH[j + 4]), us(Sh[j + 4]), P1h);                        \
      Q0h = mfma16b(us(QH[j]), us(Sh[j]), Q0h);                                \
      Q1h = mfma16b(us(QH[j + 4]), us(Sh[j + 4]), Q1h);                        \
      P0l = mfma16b(us(KH[j]), us(Sl[j]), P0l);                                \
      P1l = mfma16b(us(KH[j + 4]), us(Sl[j + 4]), P1l);                        \
      Q0l = mfma16b(us(QH[j]), us(Sl[j]), Q0l);                                \
      Q1l = mfma16b(us(QH[j + 4]), us(Sl[j + 4]), Q1l);                        \
    }                                                                          \
    /* T1 = V - P (acc layout == B-frag layout), Qt = Qhat S */                \
    f32x4 T_, Qt_;                                                             \
    _Pragma("unroll") for (int r = 0; r < 4; ++r) {                            \
      T_[r]  = VV[r] - ((P0h[r] + P1h[r]) + (P0l[r] + P1l[r]));                \
      Qt_[r] = (Q0h[r] + Q1h[r]) + (Q0l[r] + Q1l[r]);                          \
    }                                                                          \
    uint2 Thw, Tlw; packhl(T_, Thw, Tlw);                                      \
    /* U = Winv T1 (2-deep) */                                                 \
    f32x4 Ua = mfma16b(us(WH), us(Thw), z_);                                   \
    f32x4 Ub = mfma16b(us(WH), us(Tlw), z_);                                   \
    Ub = mfma16b(us(WL), us(Thw), Ub);                                         \
    f32x4 U_;                                                                  \
    _Pragma("unroll") for (int r = 0; r < 4; ++r) U_[r] = Ua[r] + Ub[r];       \
    uint2 Uhw, Ulw; packhl(U_, Uhw, Ulw);                                      \
    /* O = Qt + M U -> global (2-deep) */                                      \
    f32x4 Oa = mfma16b(us(MH), us(Uhw), Qt_);                                  \
    f32x4 Ob = mfma16b(us(MH), us(Ulw), z_);                                   \
    Ob = mfma16b(us(ML), us(Uhw), Ob);                                         \
    {                                                                          \
      float* y_ = yp + (size_t)(ch) * (CC * kV);                               \
      _Pragma("unroll") for (int r = 0; r < 4; ++r)                            \
        y_[r * kV] = Oa[r] + Ob[r];                                            \
    }                                                                          \
    /* state: S = lam (.) S + KbarT U ; repack bf16 hi/lo for next phase A */  \
    _Pragma("unroll") for (int j = 0; j < 8; ++j) {                            \
      f32x4 SLa = mfma16b(us(kb_[j]), us(Ulw), z_);                            \
      f32x4 Sv = S[j];                                                         \
      _Pragma("unroll") for (int r = 0; r < 4; ++r) Sv[r] *= lam_[j][r];       \
      Sv = mfma16b(us(kb_[j]), us(Uhw), Sv);                                   \
      _Pragma("unroll") for (int r = 0; r < 4; ++r) Sv[r] += SLa[r];           \
      S[j] = Sv;                                                               \
      packhl(Sv, Sh[j], Sl[j]);                                                \
    }                                                                          \
  }

  LKQ(khA, qhA, vA, whA, wlA, mhA, mlA, 0);
  for (int ch = 0; ch < NCH; ch += 2) {
    CHUNK(khA, qhA, vA, whA, wlA, mhA, mlA,
          khB, qhB, vB, whB, wlB, mhB, mlB, ch);
    CHUNK(khB, qhB, vB, whB, wlB, mhB, mlB,
          khA, qhA, vA, whA, wlA, mhA, mlA, ch + 1);
  }
#undef LKQ
#undef CHUNK
}

// ---------------- rmsnorm * o_norm_w * sigmoid(gate+bg) -> bf16 -----------
__global__ __launch_bounds__(256) void postk(
    const float* __restrict__ yf, const u16* __restrict__ gateb,
    const float* __restrict__ bg, const float* __restrict__ onw,
    u16* __restrict__ ygb) {
  const int wid  = blockIdx.x * 4 + (threadIdx.x >> 6);
  const int lane = threadIdx.x & 63;
  const int h  = wid & 15;
  const int bt = wid >> 4;
  const int t  = bt & (kT - 1);
  const int b  = bt >> 11;
  const int v0 = lane * 2;
  const size_t yi = ((size_t)(b * kH + h) * kT + t) * kV + v0;
  float2 yv = *(const float2*)(yf + yi);
  float s = yv.x * yv.x + yv.y * yv.y;
#pragma unroll
  for (int m = 1; m < 64; m <<= 1) s += __shfl_xor(s, m);
  float scale = rsqrtf(s * (1.0f / 128.0f) + 1.1920929e-07f);
  const size_t gi = (size_t)bt * kHV + (size_t)h * kV + v0;
  u32 ug = *(const u32*)(gateb + gi);
  float g0 = bflo(ug) + bg[h * kV + v0];
  float g1 = bfhi(ug) + bg[h * kV + v0 + 1];
  float r0 = yv.x * scale * onw[v0] * sigmoidf(g0);
  float r1 = yv.y * scale * onw[v0 + 1] * sigmoidf(g1);
  *(u32*)(ygb + gi) = (u32)f2bf(r0) | ((u32)f2bf(r1) << 16);
}

// ---------------- host launcher ----------------
extern "C" void kernel_launch(void* const* d_in, const int* in_sizes, int n_in,
                              void* d_out, int out_size, void* d_ws, size_t ws_size,
                              hipStream_t stream) {
  (void)in_sizes; (void)n_in; (void)out_size; (void)ws_size;
  const float* x    = (const float*)d_in[0];
  const float* Wq   = (const float*)d_in[1];
  const float* Wk   = (const float*)d_in[2];
  const float* Wv   = (const float*)d_in[3];
  const float* Wf1  = (const float*)d_in[4];
  const float* Wf2  = (const float*)d_in[5];
  const float* Wb   = (const float*)d_in[6];
  const float* Wg1  = (const float*)d_in[7];
  const float* Wg2  = (const float*)d_in[8];
  const float* bg   = (const float*)d_in[9];
  const float* onw  = (const float*)d_in[10];
  const float* Wout = (const float*)d_in[11];
  const float* A_log   = (const float*)d_in[12];
  const float* dt_bias = (const float*)d_in[13];
  const float* qcw  = (const float*)d_in[14];
  const float* kcw  = (const float*)d_in[15];
  const float* vcw  = (const float*)d_in[16];

  char* ws = (char*)d_ws;
  u16* xb     = (u16*)(ws + OFF_XB);
  u16* wqkv   = (u16*)(ws + OFF_WQKV);
  u16* wf1b   = (u16*)(ws + OFF_WF1B);
  u16* wg1b   = (u16*)(ws + OFF_WG1B);
  u16* wbp    = (u16*)(ws + OFF_WBP);
  u16* wf2b   = (u16*)(ws + OFF_WF2B);
  u16* wg2b   = (u16*)(ws + OFF_WG2B);
  u16* woutb  = (u16*)(ws + OFF_WOUTB);
  u16* fgb    = (u16*)(ws + OFF_FGB);
  u16* qkvraw = (u16*)(ws + OFF_QKVR);
  u16* graw   = (u16*)(ws + OFF_GRAW);
  u16* gateb  = (u16*)(ws + OFF_GATEB);
  u16* qhb    = (u16*)(ws + OFF_QHB);
  u16* khb    = (u16*)(ws + OFF_KHB);
  u16* kbb    = (u16*)(ws + OFF_KBB);
  u16* ygb    = (u16*)(ws + OFF_YGB);
  u16* whv    = (u16*)(ws + OFF_WINV);
  u16* wlv    = (u16*)(ws + OFF_WINV + 2097152);
  u16* mhv    = (u16*)(ws + OFF_MM);
  u16* mlv    = (u16*)(ws + OFF_MM + 2097152);
  float* qcf   = (float*)(ws + OFF_QC);
  float* kcf   = (float*)(ws + OFF_KC);
  float* vtf   = (float*)(ws + OFF_VT);
  float* gkf   = (float*)(ws + OFF_GK);
  float* betaf = (float*)(ws + OFF_BETA);
  float* yff   = (float*)(ws + OFF_YF);
  float* lamf  = (float*)(ws + OFF_LAM);

  cast_all<<<25600, 256, 0, stream>>>(x, Wq, Wk, Wv, Wout, Wf1, Wg1, Wf2, Wg2,
                                      xb, wqkv, woutb, wf1b, wg1b, wf2b, wg2b);
  pad_wb<<<(128 * 2048 / 4 + 255) / 256, 256, 0, stream>>>(Wb, wbp);

  dim3 blk(256);
  // qkv: [4096,6144] = x @ [Wq;Wk;Wv]^T
  gemm_bt<true><<<dim3(kM / 128, 6144 / 128), blk, 0, stream>>>(
      xb, wqkv, qkvraw, kD, kD, 6144, kD);
  // fgb: [4096,384] = x @ [Wf1;Wg1;Wbp]^T
  gemm_bt<true><<<dim3(kM / 128, 384 / 128), blk, 0, stream>>>(
      xb, wf1b, fgb, kD, kD, 384, kD);
  // graw: [4096,2048] = f1 @ Wf2^T   (A = fgb cols 0..127, lda 384)
  gemm_bt<true><<<dim3(kM / 128, kHK / 128), blk, 0, stream>>>(
      fgb, wf2b, graw, 384, kV, kHK, kV);
  // gateb: [4096,2048] = g1 @ Wg2^T  (A = fgb cols 128..255)
  gemm_bt<true><<<dim3(kM / 128, kHV / 128), blk, 0, stream>>>(
      fgb + 128, wg2b, gateb, 384, kV, kHV, kV);

  convprep<<<kB * kT * kH / 8, 256, 0, stream>>>(qkvraw, graw, fgb,
                                                 qcw, kcw, vcw, A_log, dt_bias,
                                                 qcf, kcf, vtf, gkf, betaf);

  kda_p1<<<32 * NCH, 256, 0, stream>>>(qcf, kcf, gkf, betaf,
                                       qhb, khb, kbb, lamf,
                                       whv, wlv, mhv, mlv);
  kda_p2<<<256, 64, 0, stream>>>(khb, qhb, kbb, lamf,
                                 whv, wlv, mhv, mlv, vtf, yff);

  postk<<<kB * kT * kH / 4, 256, 0, stream>>>(yff, gateb, bg, onw, ygb);

  // out: [4096,2048] = yg @ Wout^T
  gemm_bt<false><<<dim3(kM / 128, kD / 128), blk, 0, stream>>>(
      ygb, woutb, (float*)d_out, kHV, kHV, kD, kHV);
}

// Round 7
// 774.232 us; speedup vs baseline: 1.1441x; 1.1441x over previous
//
#include <hip/hip_runtime.h>

typedef unsigned short u16;
typedef unsigned int u32;

using short8 = __attribute__((ext_vector_type(8))) short;
using s4     = __attribute__((ext_vector_type(4))) short;
using f32x4  = __attribute__((ext_vector_type(4))) float;

constexpr int kB = 2, kT = 2048, kD = 2048, kH = 16, kK = 128, kV = 128;
constexpr int kM  = kB * kT;   // 4096 tokens
constexpr int kHK = kH * kK;   // 2048
constexpr int kHV = kH * kV;   // 2048
constexpr int CC  = 16;        // scan chunk length
constexpr int NCH = kT / CC;   // 128 chunks

// ---------------- workspace layout (bytes). Overlays are deliberate. -------
constexpr size_t OFF_XB    = 0;          // bf16 x [4096][2048] (dead after gemms)
constexpr size_t OFF_WQKV  = 16777216;   // bf16 [6144][2048] = Wq|Wk|Wv stacked
constexpr size_t OFF_QC    = 0;          // f32 qc [32][2048][128] (convprep out)
constexpr size_t OFF_YF    = 0;          // f32 y (p2 out; qc dead after p1)
constexpr size_t OFF_WF1B  = 41943040;   // bf16 Wf1 [128][2048]
constexpr size_t OFF_WG1B  = 42467328;   // bf16 Wg1
constexpr size_t OFF_WBP   = 42991616;   // bf16 Wb padded [128][2048]
constexpr size_t OFF_WF2B  = 43515904;   // bf16 Wf2
constexpr size_t OFF_WG2B  = 44040192;   // bf16 Wg2
constexpr size_t OFF_FGB   = 44564480;   // bf16 fgb [4096][384] (f1|g1|braw)
constexpr size_t OFF_QKVR  = 48758784;   // bf16 qkvraw [4096][6144]
constexpr size_t OFF_QHB   = 48758784;   // bf16 qhat [32][2048][128] (over qkvraw)
constexpr size_t OFF_KBB   = 65536000;   // bf16 kbar TRANSPOSED [32][128ch][128k][16t]
constexpr size_t OFF_KHB   = 82313216;   // bf16 khat
constexpr size_t OFF_YGB   = 82313216;   // bf16 y-gated (postk out, khb dead by then)
constexpr size_t OFF_GRAW  = 99090432;   // bf16 g_raw (dead after convprep)
constexpr size_t OFF_LAM   = 99090432;   // f32 lam  [32][128][128] (over graw)
constexpr size_t OFF_WINV  = 101187584;  // bf16 winv hi [32][128][16][16] | lo at +2MB
constexpr size_t OFF_MM    = 105381888;  // bf16 M hi | lo at +2MB
constexpr size_t OFF_GATEB = 115867648;  // bf16 gate [4096][2048]
constexpr size_t OFF_WOUTB = 132644864;  // bf16 Wout
constexpr size_t OFF_KC    = 141033472;  // f32 kc
constexpr size_t OFF_VT    = 174587904;  // f32 v transposed [bh*8+vs][t][16]
constexpr size_t OFF_GK    = 208142336;  // f32 log-decay g
constexpr size_t OFF_BETA  = 241696768;  // f32 beta [32][2048]
// total 241958912 bytes (~231 MB), unchanged

// ---------------- small helpers ----------------
__device__ __forceinline__ u16 f2bf(float f) {
  union { float f; u32 u; } a; a.f = f;
  u32 u = a.u;
  u += 0x7fffu + ((u >> 16) & 1u);   // round-to-nearest-even
  return (u16)(u >> 16);
}
__device__ __forceinline__ float bflo(u32 u) {
  union { u32 u; float f; } a; a.u = u << 16; return a.f;
}
__device__ __forceinline__ float bfhi(u32 u) {
  union { u32 u; float f; } a; a.u = u & 0xffff0000u; return a.f;
}
union BU { uint2 u; s4 s; };
__device__ __forceinline__ s4 us(uint2 u) { BU x; x.u = u; return x.s; }
// fast sigmoid: v_exp + v_rcp (~1 ulp each; all consumers round to bf16)
__device__ __forceinline__ float sigmoidf(float x) {
  return __builtin_amdgcn_rcpf(1.0f + __expf(-x));
}
// 16x16x16 bf16 MFMA. Fragment layouts (HW-verified by R5/R6 passing):
// A: row=lane&15, k=(lane>>4)*4+i ; B: k=(lane>>4)*4+i, col=lane&15 ;
// C/D: row=(lane>>4)*4+r, col=lane&15  -> D layout == B layout (chainable).
__device__ __forceinline__ f32x4 mfma16b(s4 a, s4 b, f32x4 c) {
  return __builtin_amdgcn_mfma_f32_16x16x16bf16_1k(a, b, c, 0, 0, 0);
}
// pack f32x4 (D-frag) into bf16 hi + lo uint2 pair (unscaled; bf16 keeps the
// f32 exponent range so lo parts never denormalize)
__device__ __forceinline__ void packhl(const f32x4& v, uint2& hw, uint2& lw) {
  u16 h0 = f2bf(v[0]), h1 = f2bf(v[1]), h2 = f2bf(v[2]), h3 = f2bf(v[3]);
  hw.x = (u32)h0 | ((u32)h1 << 16); hw.y = (u32)h2 | ((u32)h3 << 16);
  lw.x = (u32)f2bf(v[0] - bflo(h0)) | ((u32)f2bf(v[1] - bflo(h1)) << 16);
  lw.y = (u32)f2bf(v[2] - bflo(h2)) | ((u32)f2bf(v[3] - bflo(h3)) << 16);
}

#define GL_AS1 __attribute__((address_space(1)))
#define GL_AS3 __attribute__((address_space(3)))
__device__ __forceinline__ void async_lds16(const void* g, void* l) {
  __builtin_amdgcn_global_load_lds((GL_AS1 u32*)(size_t)g,
                                   (GL_AS3 u32*)(u32)(size_t)l, 16, 0, 0);
}

// ---------------- fused cast of all f32->bf16 weights/x --------------------
__global__ __launch_bounds__(256) void cast_all(
    const float* __restrict__ x, const float* __restrict__ Wq,
    const float* __restrict__ Wk, const float* __restrict__ Wv,
    const float* __restrict__ Wout, const float* __restrict__ Wf1,
    const float* __restrict__ Wg1, const float* __restrict__ Wf2,
    const float* __restrict__ Wg2,
    u16* __restrict__ xb, u16* __restrict__ wqkv, u16* __restrict__ woutb,
    u16* __restrict__ wf1b, u16* __restrict__ wg1b, u16* __restrict__ wf2b,
    u16* __restrict__ wg2b) {
  long qi = (long)blockIdx.x * 256 + threadIdx.x;   // float4 index
  const float* src; u16* dst; long off;
  if (qi < 2097152)      { src = x;    dst = xb;             off = qi; }
  else if (qi < 3145728) { src = Wq;   dst = wqkv;           off = qi - 2097152; }
  else if (qi < 4194304) { src = Wk;   dst = wqkv + 4194304; off = qi - 3145728; }
  else if (qi < 5242880) { src = Wv;   dst = wqkv + 8388608; off = qi - 4194304; }
  else if (qi < 6291456) { src = Wout; dst = woutb;          off = qi - 5242880; }
  else if (qi < 6356992) { src = Wf1;  dst = wf1b;           off = qi - 6291456; }
  else if (qi < 6422528) { src = Wg1;  dst = wg1b;           off = qi - 6356992; }
  else if (qi < 6488064) { src = Wf2;  dst = wf2b;           off = qi - 6422528; }
  else                   { src = Wg2;  dst = wg2b;           off = qi - 6488064; }
  long i = off * 4;
  float4 v = *(const float4*)(src + i);
  uint2 st;
  st.x = (u32)f2bf(v.x) | ((u32)f2bf(v.y) << 16);
  st.y = (u32)f2bf(v.z) | ((u32)f2bf(v.w) << 16);
  *(uint2*)(dst + i) = st;
}

// Wb [16,2048] f32 -> [128,2048] bf16 zero-padded
__global__ __launch_bounds__(256) void pad_wb(const float* __restrict__ Wb,
                                              u16* __restrict__ out) {
  int i = (blockIdx.x * 256 + threadIdx.x) * 4;  // < 262144
  int row = i >> 11;
  uint2 st; st.x = 0; st.y = 0;
  if (row < 16) {
    float4 v = *(const float4*)(Wb + i);
    st.x = (u32)f2bf(v.x) | ((u32)f2bf(v.y) << 16);
    st.y = (u32)f2bf(v.z) | ((u32)f2bf(v.w) << 16);
  }
  *(uint2*)(out + i) = st;
}

// ---------------- bf16 MFMA GEMM:  C[m,n] = sum_k A[m,k] * B[n,k] ----------
template <bool BF16OUT>
__global__ __launch_bounds__(256) void gemm_bt(const u16* __restrict__ A,
                                               const u16* __restrict__ B,
                                               void* __restrict__ Cout,
                                               int lda, int ldb, int ldc, int K) {
  __shared__ u16 As[128 * 32];
  __shared__ u16 Bs[128 * 32];
  const int tid  = threadIdx.x;
  const int lane = tid & 63;
  const int wave = tid >> 6;
  const int wm = (wave >> 1) * 64;
  const int wn = (wave & 1) * 64;
  const long row0 = (long)blockIdx.x * 128;
  const long col0 = (long)blockIdx.y * 128;
  const int srow = tid >> 2;
  const int scol = (tid & 3) * 8;
  const u16* aptr = A + (row0 + srow) * (size_t)lda + scol;
  const u16* bptr = B + (col0 + srow) * (size_t)ldb + scol;
  u16* asd  = &As[tid * 8];
  u16* asd2 = &As[2048 + tid * 8];
  u16* bsd  = &Bs[tid * 8];
  u16* bsd2 = &Bs[2048 + tid * 8];
  const int mrow = lane & 15;
  const int kq = (lane >> 4) * 8;
  f32x4 acc[4][4] = {};
  for (int k0 = 0; k0 < K; k0 += 32) {
    async_lds16(aptr, asd);
    async_lds16(aptr + (size_t)64 * lda, asd2);
    async_lds16(bptr, bsd);
    async_lds16(bptr + (size_t)64 * ldb, bsd2);
    aptr += 32; bptr += 32;
    __syncthreads();
    short8 af[4], bfr[4];
#pragma unroll
    for (int i = 0; i < 4; ++i)
      af[i] = *(const short8*)(&As[(wm + i * 16 + mrow) * 32 + kq]);
#pragma unroll
    for (int j = 0; j < 4; ++j)
      bfr[j] = *(const short8*)(&Bs[(wn + j * 16 + mrow) * 32 + kq]);
#pragma unroll
    for (int i = 0; i < 4; ++i)
#pragma unroll
      for (int j = 0; j < 4; ++j)
        acc[i][j] = __builtin_amdgcn_mfma_f32_16x16x32_bf16(af[i], bfr[j], acc[i][j], 0, 0, 0);
    __syncthreads();
  }
  const int cn = lane & 15;
  const int rq = (lane >> 4) * 4;
#pragma unroll
  for (int i = 0; i < 4; ++i)
#pragma unroll
    for (int j = 0; j < 4; ++j) {
      size_t r = (size_t)(row0 + wm + i * 16 + rq);
      size_t c = (size_t)(col0 + wn + j * 16 + cn);
#pragma unroll
      for (int rr = 0; rr < 4; ++rr) {
        if constexpr (BF16OUT)
          ((u16*)Cout)[(r + rr) * ldc + c] = f2bf(acc[i][j][rr]);
        else
          ((float*)Cout)[(r + rr) * ldc + c] = acc[i][j][rr];
      }
    }
}

// ---------------- conv(4-tap causal) + silu + l2norm + g + beta ------------
__global__ __launch_bounds__(256) void convprep(
    const u16* __restrict__ qkv, const u16* __restrict__ graw,
    const u16* __restrict__ fgb,
    const float* __restrict__ qcw, const float* __restrict__ kcw,
    const float* __restrict__ vcw, const float* __restrict__ A_log,
    const float* __restrict__ dt_bias,
    float* __restrict__ qc, float* __restrict__ kc, float* __restrict__ vt,
    float* __restrict__ gdec, float* __restrict__ beta) {
  const int wid = blockIdx.x * 8 + (threadIdx.x >> 5);  // (b*T+t)*H + h
  const int l32 = threadIdx.x & 31;
  const int h  = wid & 15;
  const int bt = wid >> 4;        // b*T + t
  const int t  = bt & (kT - 1);
  const int b  = bt >> 11;
  const int c0 = l32 * 4;
  const size_t colofs = (size_t)h * kK + c0;
  const size_t rowb = (size_t)bt * 6144 + colofs;
  float wqt[4][4], wkt[4][4], wvt[4][4];
#pragma unroll
  for (int j = 0; j < 4; ++j) {
    *(float4*)wqt[j] = *(const float4*)(qcw + (colofs + j) * 4);
    *(float4*)wkt[j] = *(const float4*)(kcw + (colofs + j) * 4);
    *(float4*)wvt[j] = *(const float4*)(vcw + (colofs + j) * 4);
  }
  float qa[4] = {0.f, 0.f, 0.f, 0.f};
  float ka[4] = {0.f, 0.f, 0.f, 0.f};
  float va[4] = {0.f, 0.f, 0.f, 0.f};
#pragma unroll
  for (int i = 0; i < 4; ++i) {
    int tt = t - 3 + i;
    if (tt >= 0) {   // wave-uniform branch
      size_t ro = rowb - (size_t)(3 - i) * 6144;
      uint2 uq = *(const uint2*)(qkv + ro);
      uint2 uk = *(const uint2*)(qkv + ro + 2048);
      uint2 uv = *(const uint2*)(qkv + ro + 4096);
      float q0 = bflo(uq.x), q1 = bfhi(uq.x), q2 = bflo(uq.y), q3 = bfhi(uq.y);
      float k0 = bflo(uk.x), k1 = bfhi(uk.x), k2 = bflo(uk.y), k3 = bfhi(uk.y);
      float v0 = bflo(uv.x), v1 = bfhi(uv.x), v2 = bflo(uv.y), v3 = bfhi(uv.y);
      qa[0] = fmaf(q0, wqt[0][i], qa[0]); qa[1] = fmaf(q1, wqt[1][i], qa[1]);
      qa[2] = fmaf(q2, wqt[2][i], qa[2]); qa[3] = fmaf(q3, wqt[3][i], qa[3]);
      ka[0] = fmaf(k0, wkt[0][i], ka[0]); ka[1] = fmaf(k1, wkt[1][i], ka[1]);
      ka[2] = fmaf(k2, wkt[2][i], ka[2]); ka[3] = fmaf(k3, wkt[3][i], ka[3]);
      va[0] = fmaf(v0, wvt[0][i], va[0]); va[1] = fmaf(v1, wvt[1][i], va[1]);
      va[2] = fmaf(v2, wvt[2][i], va[2]); va[3] = fmaf(v3, wvt[3][i], va[3]);
    }
  }
  float sq = 0.f, sk = 0.f;
#pragma unroll
  for (int j = 0; j < 4; ++j) {
    qa[j] *= sigmoidf(qa[j]);            // silu
    ka[j] *= sigmoidf(ka[j]);
    va[j] *= sigmoidf(va[j]);
    sq = fmaf(qa[j], qa[j], sq);
    sk = fmaf(ka[j], ka[j], sk);
  }
#pragma unroll
  for (int m = 1; m < 32; m <<= 1) {     // reduce within the 32-lane row
    sq += __shfl_xor(sq, m);
    sk += __shfl_xor(sk, m);
  }
  float qinv = __builtin_amdgcn_rcpf(fmaxf(__builtin_amdgcn_sqrtf(sq), 1e-12f));
  float kinv = __builtin_amdgcn_rcpf(fmaxf(__builtin_amdgcn_sqrtf(sk), 1e-12f));
  const int bh = b * kH + h;
  const size_t outb = ((size_t)bh * kT + t) * kK + c0;
  *(float4*)(qc + outb) =
      make_float4(qa[0] * qinv, qa[1] * qinv, qa[2] * qinv, qa[3] * qinv);
  *(float4*)(kc + outb) =
      make_float4(ka[0] * kinv, ka[1] * kinv, ka[2] * kinv, ka[3] * kinv);
  const size_t vtb = ((size_t)(bh * 8 + (c0 >> 4)) * kT + t) * 16 + (c0 & 15);
  *(float4*)(vt + vtb) = make_float4(va[0], va[1], va[2], va[3]);
  uint2 ug = *(const uint2*)(graw + (size_t)bt * kHK + colofs);
  float Ae = __expf(A_log[h]);
  float4 db = *(const float4*)(dt_bias + colofs);
  float g0 = bflo(ug.x) + db.x;
  float g1 = bfhi(ug.x) + db.y;
  float g2 = bflo(ug.y) + db.z;
  float g3 = bfhi(ug.y) + db.w;
  float sp0 = (g0 > 15.f) ? g0 : __logf(1.f + __expf(g0));
  float sp1 = (g1 > 15.f) ? g1 : __logf(1.f + __expf(g1));
  float sp2 = (g2 > 15.f) ? g2 : __logf(1.f + __expf(g2));
  float sp3 = (g3 > 15.f) ? g3 : __logf(1.f + __expf(g3));
  *(float4*)(gdec + outb) = make_float4(-Ae * sp0, -Ae * sp1, -Ae * sp2, -Ae * sp3);
  if (l32 == 0) {
    float bv = bflo((u32)fgb[(size_t)bt * 384 + 256 + h]);
    beta[(size_t)bh * kT + t] = sigmoidf(bv);
  }
}

// ---------------- KDA pass 1: per (bh,chunk) transforms --------------------
// Emits BF16 khat=k*e^G, qhat=q*e^G (layout [t][k]); kbar=k*e^{GC-G} written
// TRANSPOSED per chunk ([k][16 t]). f32 lam=e^{GC}. Winv=(I+B trilA)^{-1}B
// and M emitted as BF16 hi+lo pairs. Everything built from the bf16-ROUNDED
// khat/qhat/kbar so the chunk algebra is exactly consistent with p2's bf16
// MFMA operands.
__global__ __launch_bounds__(256) void kda_p1(
    const float* __restrict__ qc, const float* __restrict__ kc,
    const float* __restrict__ gk, const float* __restrict__ betap,
    u16* __restrict__ qhb, u16* __restrict__ khb, u16* __restrict__ kbt,
    float* __restrict__ lamC, u16* __restrict__ whv, u16* __restrict__ wlv,
    u16* __restrict__ mhv, u16* __restrict__ mlv) {
  __shared__ float kL[CC][132], qL[CC][132], gL[CC][132];
  __shared__ float As[CC][CC], Ms[CC][CC];
  __shared__ float bet[CC];
  const int tid = threadIdx.x;
  const int bh = blockIdx.x >> 7;
  const int ch = blockIdx.x & 127;
  const size_t base = ((size_t)bh * kT + ch * CC) * kK;
  const int e = tid * 8;
  const int t = e >> 7, k = e & 127;
  {
    *(float4*)&kL[t][k]     = *(const float4*)(kc + base + e);
    *(float4*)&kL[t][k + 4] = *(const float4*)(kc + base + e + 4);
    *(float4*)&qL[t][k]     = *(const float4*)(qc + base + e);
    *(float4*)&qL[t][k + 4] = *(const float4*)(qc + base + e + 4);
    *(float4*)&gL[t][k]     = *(const float4*)(gk + base + e);
    *(float4*)&gL[t][k + 4] = *(const float4*)(gk + base + e + 4);
    if (tid < CC) bet[tid] = betap[(size_t)bh * kT + ch * CC + tid];
  }
  __syncthreads();
  if (tid < kK) {        // inclusive cumsum of g over t -> G
    float a = gL[0][tid];
#pragma unroll
    for (int tt = 1; tt < CC; ++tt) { a += gL[tt][tid]; gL[tt][tid] = a; }
  }
  __syncthreads();
  float khr[8], qhr[8], kbw[8];
  u16 kbv[8];
  u32 pk[4] = {0,0,0,0}, pq[4] = {0,0,0,0};
#pragma unroll
  for (int j = 0; j < 8; ++j) {
    float G  = gL[t][k + j];
    float GC = gL[CC - 1][k + j];
    float eg = __expf(G);
    float kh = kL[t][k + j] * eg;
    float qh = qL[t][k + j] * eg;
    float kb = kL[t][k + j] * __expf(GC - G);
    u16 a = f2bf(kh), b_ = f2bf(qh), c = f2bf(kb);
    pk[j >> 1] |= ((u32)a)  << (16 * (j & 1));
    pq[j >> 1] |= ((u32)b_) << (16 * (j & 1));
    kbv[j] = c;
    khr[j] = bflo((u32)a);
    qhr[j] = bflo((u32)b_);
    kbw[j] = bflo((u32)c) * __expf(-GC);   // kbar * e^{-GC} (bf16: no underflow)
  }
  *(uint4*)(khb + base + e) = *(uint4*)pk;
  *(uint4*)(qhb + base + e) = *(uint4*)pq;
  {  // transposed kbar: [bh][ch][k][16 t]
    const size_t kb2 = ((size_t)bh * NCH + ch) * (size_t)(kK * CC) +
                       (size_t)k * CC + t;
#pragma unroll
    for (int j = 0; j < 8; ++j) kbt[kb2 + (size_t)j * CC] = kbv[j];
  }
  if (tid < kK)
    lamC[((size_t)bh * NCH + ch) * kK + tid] = __expf(gL[CC - 1][tid]);
  __syncthreads();   // all GC reads done before overwrite
#pragma unroll
  for (int j = 0; j < 8; ++j) {
    kL[t][k + j] = khr[j];
    qL[t][k + j] = qhr[j];
    gL[t][k + j] = kbw[j];
  }
  __syncthreads();
  {  // A[t][s]=khat_t . (kbar_s e^{-GC}); M[t][s]=qhat_t . (kbar_s e^{-GC})
    const int t2 = tid >> 4, s = tid & 15;
    float av = 0.f, mv = 0.f;
    for (int kk = 0; kk < kK; ++kk) {
      float w = gL[s][kk];
      av = fmaf(kL[t2][kk], w, av);
      mv = fmaf(qL[t2][kk], w, mv);
    }
    As[t2][s] = (s < t2)  ? av : 0.f;
    Ms[t2][s] = (s <= t2) ? mv : 0.f;
  }
  __syncthreads();
  const size_t smb = ((size_t)bh * NCH + ch) * 256;
  if (tid < CC) {  // X = (I + B trilA)^{-1} B, column s -> bf16 hi+lo
    const int s = tid;
    float x[CC];
#pragma unroll
    for (int tt = 0; tt < CC; ++tt) {
      float sum = 0.f;
      for (int r = 0; r < tt; ++r) sum += As[tt][r] * x[r];
      x[tt] = ((tt == s) ? bet[tt] : 0.f) - bet[tt] * sum;
    }
#pragma unroll
    for (int tt = 0; tt < CC; ++tt) {
      u16 xh = f2bf(x[tt]);
      whv[smb + tt * 16 + s] = xh;
      wlv[smb + tt * 16 + s] = f2bf(x[tt] - bflo((u32)xh));
    }
  }
  {
    float mvv = Ms[tid >> 4][tid & 15];
    u16 mhh = f2bf(mvv);
    mhv[smb + tid] = mhh;
    mlv[smb + tid] = f2bf(mvv - bflo((u32)mhh));
  }
}

// ---------------- KDA pass 2: 4-wave block, register state, 1 barrier ------
// 64 blocks = 32 bh x 2 column-halves. 4 waves; wave w owns v-cols
// [g*64+16w, +16) with its FULL 128x16 state in registers (v-columns are
// independent scans; D-layout == B-layout chaining, R5/R6-proven algebra).
// Shared per-chunk operands (khat,qhat,kbar,lam,Winv,M,V) are staged
// global->reg->padded LDS, double-buffered: loads for ch+1 issue before
// chunk ch's compute (~full chunk of latency cover), LDS writes land after,
// ONE __syncthreads per chunk. All LDS strides padded (136/20/68) ->
// <=2-way bank conflicts (free). 64 blocks < 256 CUs: every block owns a CU;
// blk&31=bh keeps both halves of a bh on one XCD (L2 reuse).
__global__ __launch_bounds__(256, 1) void kda_p2(
    const u16* __restrict__ khb, const u16* __restrict__ qhb,
    const u16* __restrict__ kbt, const float* __restrict__ lamC,
    const u16* __restrict__ whg, const u16* __restrict__ wlg,
    const u16* __restrict__ mhg, const u16* __restrict__ mlg,
    const float* __restrict__ vt, float* __restrict__ yf) {
  __shared__ u16 khs[2][CC][136];
  __shared__ u16 qhs[2][CC][136];
  __shared__ u16 kbs[2][kK][20];     // [k][t], stride 20 -> conflict-free frags
  __shared__ float vsx[2][CC][68];   // [t][64 v-cols + pad]
  __shared__ u16 whs[2][CC][20], wls[2][CC][20];
  __shared__ u16 mhs[2][CC][20], mls[2][CC][20];
  __shared__ float lamx[2][kK];
  const int tid = threadIdx.x;
  const int w = tid >> 6, lane = tid & 63;
  const int m15 = lane & 15, q = lane >> 4;
  const int blk = blockIdx.x;
  const int bh = blk & 31, g = blk >> 5;
  const size_t khbase = (size_t)bh * (kT * kK);
  const size_t kbbase = (size_t)bh * (NCH * (kK * CC));
  const size_t smbase = (size_t)bh * (NCH * 256);
  const int tv = (tid & 63) >> 2, c4 = (tid & 3) * 4;   // v-staging coords

  f32x4 S[8] = {};               // state tiles: k in [16j,16j+16), col v
  uint2 Sh[8] = {}, Sl[8] = {};  // state as bf16 hi/lo B-frags

  uint4 rkh, rqh, rkb; float4 rv; u32 rw, rl2, rm, rml; float rlam;
  auto loadR = [&](int ch) {
    const size_t cb = khbase + (size_t)ch * (CC * kK) + tid * 8;
    rkh = *(const uint4*)(khb + cb);
    rqh = *(const uint4*)(qhb + cb);
    rkb = *(const uint4*)(kbt + kbbase + (size_t)ch * (kK * CC) + tid * 8);
    rv  = *(const float4*)(vt +
          ((size_t)(bh * 8 + g * 4 + w) * kT + ch * CC + tv) * 16 + c4);
    if (tid < 128) {
      const size_t sm = smbase + (size_t)ch * 256;
      rw  = *(const u32*)(whg + sm + tid * 2);
      rl2 = *(const u32*)(wlg + sm + tid * 2);
      rm  = *(const u32*)(mhg + sm + tid * 2);
      rml = *(const u32*)(mlg + sm + tid * 2);
      rlam = lamC[(size_t)bh * (NCH * kK) + (size_t)ch * kK + tid];
    }
  };
  auto writeS = [&](int b) {
    const int tr = tid >> 4, tc = (tid & 15) * 8;
    *(uint4*)&khs[b][tr][tc] = rkh;
    *(uint4*)&qhs[b][tr][tc] = rqh;
    u16* kd = &kbs[b][tid >> 1][(tid & 1) * 8];   // stride 40B: 2x 8B writes
    *(uint2*)kd = make_uint2(rkb.x, rkb.y);
    *(uint2*)(kd + 4) = make_uint2(rkb.z, rkb.w);
    *(float4*)&vsx[b][tv][w * 16 + c4] = rv;
    if (tid < 128) {
      const int wr = tid >> 3, wc = (tid & 7) * 2;
      *(u32*)&whs[b][wr][wc] = rw;
      *(u32*)&wls[b][wr][wc] = rl2;
      *(u32*)&mhs[b][wr][wc] = rm;
      *(u32*)&mls[b][wr][wc] = rml;
      lamx[b][tid] = rlam;
    }
  };

  float* yp = yf + ((size_t)bh * kT + 4 * q) * kV + g * 64 + w * 16 + m15;

  loadR(0);
  writeS(0);
  __syncthreads();
  for (int ch = 0; ch < NCH; ++ch) {
    const int b = ch & 1;
    if (ch + 1 < NCH) loadR(ch + 1);   // global loads overlap compute below
    // ---- phase A: P = Khat S, Q = Qhat S (split hi/lo accumulators) ----
    f32x4 z = {0.f, 0.f, 0.f, 0.f};
    f32x4 Ph = z, Pl = z, Qh = z, Ql = z;
#pragma unroll
    for (int j = 0; j < 8; ++j) {
      s4 aK = *(const s4*)&khs[b][m15][16 * j + 4 * q];
      s4 aQ = *(const s4*)&qhs[b][m15][16 * j + 4 * q];
      Ph = mfma16b(aK, us(Sh[j]), Ph);
      Pl = mfma16b(aK, us(Sl[j]), Pl);
      Qh = mfma16b(aQ, us(Sh[j]), Qh);
      Ql = mfma16b(aQ, us(Sl[j]), Ql);
    }
    // ---- T1 = V - P ; Qt ----
    f32x4 T_, Qt;
#pragma unroll
    for (int r = 0; r < 4; ++r) {
      float vv = vsx[b][4 * q + r][16 * w + m15];
      T_[r] = vv - (Ph[r] + Pl[r]);
      Qt[r] = Qh[r] + Ql[r];
    }
    uint2 Thw, Tlw; packhl(T_, Thw, Tlw);
    // ---- U = Winv T1 ----
    s4 aWh = *(const s4*)&whs[b][m15][4 * q];
    s4 aWl = *(const s4*)&wls[b][m15][4 * q];
    f32x4 Ua = mfma16b(aWh, us(Thw), z);
    f32x4 Ub = mfma16b(aWh, us(Tlw), z);
    Ub = mfma16b(aWl, us(Thw), Ub);
    f32x4 U_;
#pragma unroll
    for (int r = 0; r < 4; ++r) U_[r] = Ua[r] + Ub[r];
    uint2 Uhw, Ulw; packhl(U_, Uhw, Ulw);
    // ---- O = Qt + M U -> global ----
    s4 aMh = *(const s4*)&mhs[b][m15][4 * q];
    s4 aMl = *(const s4*)&mls[b][m15][4 * q];
    f32x4 Oa = mfma16b(aMh, us(Uhw), Qt);
    f32x4 Ob = mfma16b(aMh, us(Ulw), z);
    Ob = mfma16b(aMl, us(Uhw), Ob);
    {
      float* y_ = yp + (size_t)ch * (CC * kV);
#pragma unroll
      for (int r = 0; r < 4; ++r) y_[r * kV] = Oa[r] + Ob[r];
    }
    // ---- state: S = lam (.) S + KbarT U ; repack hi/lo ----
#pragma unroll
    for (int j = 0; j < 8; ++j) {
      s4 aB = *(const s4*)&kbs[b][16 * j + m15][4 * q];
      f32x4 SLa = mfma16b(aB, us(Ulw), z);
      f32x4 Sv = S[j];
      float4 lm = *(const float4*)&lamx[b][16 * j + 4 * q];
      Sv[0] *= lm.x; Sv[1] *= lm.y; Sv[2] *= lm.z; Sv[3] *= lm.w;
      Sv = mfma16b(aB, us(Uhw), Sv);
#pragma unroll
      for (int r = 0; r < 4; ++r) Sv[r] += SLa[r];
      S[j] = Sv;
      packhl(Sv, Sh[j], Sl[j]);
    }
    // ---- stage next chunk into the other buffer ----
    if (ch + 1 < NCH) writeS(b ^ 1);
    __syncthreads();
  }
}

// ---------------- rmsnorm * o_norm_w * sigmoid(gate+bg) -> bf16 -----------
__global__ __launch_bounds__(256) void postk(
    const float* __restrict__ yf, const u16* __restrict__ gateb,
    const float* __restrict__ bg, const float* __restrict__ onw,
    u16* __restrict__ ygb) {
  const int wid  = blockIdx.x * 4 + (threadIdx.x >> 6);
  const int lane = threadIdx.x & 63;
  const int h  = wid & 15;
  const int bt = wid >> 4;
  const int t  = bt & (kT - 1);
  const int b  = bt >> 11;
  const int v0 = lane * 2;
  const size_t yi = ((size_t)(b * kH + h) * kT + t) * kV + v0;
  float2 yv = *(const float2*)(yf + yi);
  float s = yv.x * yv.x + yv.y * yv.y;
#pragma unroll
  for (int m = 1; m < 64; m <<= 1) s += __shfl_xor(s, m);
  float scale = rsqrtf(s * (1.0f / 128.0f) + 1.1920929e-07f);
  const size_t gi = (size_t)bt * kHV + (size_t)h * kV + v0;
  u32 ug = *(const u32*)(gateb + gi);
  float g0 = bflo(ug) + bg[h * kV + v0];
  float g1 = bfhi(ug) + bg[h * kV + v0 + 1];
  float r0 = yv.x * scale * onw[v0] * sigmoidf(g0);
  float r1 = yv.y * scale * onw[v0 + 1] * sigmoidf(g1);
  *(u32*)(ygb + gi) = (u32)f2bf(r0) | ((u32)f2bf(r1) << 16);
}

// ---------------- host launcher ----------------
extern "C" void kernel_launch(void* const* d_in, const int* in_sizes, int n_in,
                              void* d_out, int out_size, void* d_ws, size_t ws_size,
                              hipStream_t stream) {
  (void)in_sizes; (void)n_in; (void)out_size; (void)ws_size;
  const float* x    = (const float*)d_in[0];
  const float* Wq   = (const float*)d_in[1];
  const float* Wk   = (const float*)d_in[2];
  const float* Wv   = (const float*)d_in[3];
  const float* Wf1  = (const float*)d_in[4];
  const float* Wf2  = (const float*)d_in[5];
  const float* Wb   = (const float*)d_in[6];
  const float* Wg1  = (const float*)d_in[7];
  const float* Wg2  = (const float*)d_in[8];
  const float* bg   = (const float*)d_in[9];
  const float* onw  = (const float*)d_in[10];
  const float* Wout = (const float*)d_in[11];
  const float* A_log   = (const float*)d_in[12];
  const float* dt_bias = (const float*)d_in[13];
  const float* qcw  = (const float*)d_in[14];
  const float* kcw  = (const float*)d_in[15];
  const float* vcw  = (const float*)d_in[16];

  char* ws = (char*)d_ws;
  u16* xb     = (u16*)(ws + OFF_XB);
  u16* wqkv   = (u16*)(ws + OFF_WQKV);
  u16* wf1b   = (u16*)(ws + OFF_WF1B);
  u16* wg1b   = (u16*)(ws + OFF_WG1B);
  u16* wbp    = (u16*)(ws + OFF_WBP);
  u16* wf2b   = (u16*)(ws + OFF_WF2B);
  u16* wg2b   = (u16*)(ws + OFF_WG2B);
  u16* woutb  = (u16*)(ws + OFF_WOUTB);
  u16* fgb    = (u16*)(ws + OFF_FGB);
  u16* qkvraw = (u16*)(ws + OFF_QKVR);
  u16* graw   = (u16*)(ws + OFF_GRAW);
  u16* gateb  = (u16*)(ws + OFF_GATEB);
  u16* qhb    = (u16*)(ws + OFF_QHB);
  u16* khb    = (u16*)(ws + OFF_KHB);
  u16* kbb    = (u16*)(ws + OFF_KBB);
  u16* ygb    = (u16*)(ws + OFF_YGB);
  u16* whv    = (u16*)(ws + OFF_WINV);
  u16* wlv    = (u16*)(ws + OFF_WINV + 2097152);
  u16* mhv    = (u16*)(ws + OFF_MM);
  u16* mlv    = (u16*)(ws + OFF_MM + 2097152);
  float* qcf   = (float*)(ws + OFF_QC);
  float* kcf   = (float*)(ws + OFF_KC);
  float* vtf   = (float*)(ws + OFF_VT);
  float* gkf   = (float*)(ws + OFF_GK);
  float* betaf = (float*)(ws + OFF_BETA);
  float* yff   = (float*)(ws + OFF_YF);
  float* lamf  = (float*)(ws + OFF_LAM);

  cast_all<<<25600, 256, 0, stream>>>(x, Wq, Wk, Wv, Wout, Wf1, Wg1, Wf2, Wg2,
                                      xb, wqkv, woutb, wf1b, wg1b, wf2b, wg2b);
  pad_wb<<<(128 * 2048 / 4 + 255) / 256, 256, 0, stream>>>(Wb, wbp);

  dim3 blk(256);
  // qkv: [4096,6144] = x @ [Wq;Wk;Wv]^T
  gemm_bt<true><<<dim3(kM / 128, 6144 / 128), blk, 0, stream>>>(
      xb, wqkv, qkvraw, kD, kD, 6144, kD);
  // fgb: [4096,384] = x @ [Wf1;Wg1;Wbp]^T
  gemm_bt<true><<<dim3(kM / 128, 384 / 128), blk, 0, stream>>>(
      xb, wf1b, fgb, kD, kD, 384, kD);
  // graw: [4096,2048] = f1 @ Wf2^T   (A = fgb cols 0..127, lda 384)
  gemm_bt<true><<<dim3(kM / 128, kHK / 128), blk, 0, stream>>>(
      fgb, wf2b, graw, 384, kV, kHK, kV);
  // gateb: [4096,2048] = g1 @ Wg2^T  (A = fgb cols 128..255)
  gemm_bt<true><<<dim3(kM / 128, kHV / 128), blk, 0, stream>>>(
      fgb + 128, wg2b, gateb, 384, kV, kHV, kV);

  convprep<<<kB * kT * kH / 8, 256, 0, stream>>>(qkvraw, graw, fgb,
                                                 qcw, kcw, vcw, A_log, dt_bias,
                                                 qcf, kcf, vtf, gkf, betaf);

  kda_p1<<<32 * NCH, 256, 0, stream>>>(qcf, kcf, gkf, betaf,
                                       qhb, khb, kbb, lamf,
                                       whv, wlv, mhv, mlv);
  kda_p2<<<64, 256, 0, stream>>>(khb, qhb, kbb, lamf,
                                 whv, wlv, mhv, mlv, vtf, yff);

  postk<<<kB * kT * kH / 4, 256, 0, stream>>>(yff, gateb, bg, onw, ygb);

  // out: [4096,2048] = yg @ Wout^T
  gemm_bt<false><<<dim3(kM / 128, kD / 128), blk, 0, stream>>>(
      ygb, woutb, (float*)d_out, kHV, kHV, kD, kHV);
}

// Round 8
// 723.435 us; speedup vs baseline: 1.2245x; 1.0702x over previous
//
#include <hip/hip_runtime.h>

typedef unsigned short u16;
typedef unsigned int u32;

using short8 = __attribute__((ext_vector_type(8))) short;
using s4     = __attribute__((ext_vector_type(4))) short;
using f32x4  = __attribute__((ext_vector_type(4))) float;

constexpr int kB = 2, kT = 2048, kD = 2048, kH = 16, kK = 128, kV = 128;
constexpr int kM  = kB * kT;   // 4096 tokens
constexpr int kHK = kH * kK;   // 2048
constexpr int kHV = kH * kV;   // 2048
constexpr int CC  = 16;        // scan chunk length
constexpr int NCH = kT / CC;   // 128 chunks

// ---------------- workspace layout (bytes). Overlays are deliberate. -------
constexpr size_t OFF_XB    = 0;          // bf16 x [4096][2048] (dead after gemms)
constexpr size_t OFF_WQKV  = 16777216;   // bf16 [6144][2048] = Wq|Wk|Wv stacked
constexpr size_t OFF_QC    = 0;          // f32 qc [32][2048][128] (convprep out)
constexpr size_t OFF_YF    = 0;          // f32 y (p2 out; qc dead after p1)
constexpr size_t OFF_WF1B  = 41943040;   // bf16 Wf1 [128][2048]
constexpr size_t OFF_WG1B  = 42467328;   // bf16 Wg1
constexpr size_t OFF_WBP   = 42991616;   // bf16 Wb padded [128][2048]
constexpr size_t OFF_WF2B  = 43515904;   // bf16 Wf2
constexpr size_t OFF_WG2B  = 44040192;   // bf16 Wg2
constexpr size_t OFF_FGB   = 44564480;   // bf16 fgb [4096][384] (f1|g1|braw)
constexpr size_t OFF_QKVR  = 48758784;   // bf16 qkvraw [4096][6144]
constexpr size_t OFF_QHB   = 48758784;   // bf16 qhat [32][2048][128] (over qkvraw)
constexpr size_t OFF_KBB   = 65536000;   // bf16 kbar TRANSPOSED [32][128ch][128k][16t]
constexpr size_t OFF_KHB   = 82313216;   // bf16 khat
constexpr size_t OFF_YGB   = 82313216;   // bf16 y-gated (postk out, khb dead by then)
constexpr size_t OFF_GRAW  = 99090432;   // bf16 g_raw (dead after convprep)
constexpr size_t OFF_LAM   = 99090432;   // f32 lam  [32][128][128] (over graw)
constexpr size_t OFF_WINV  = 101187584;  // f32 winv [32][128][256]
constexpr size_t OFF_MM    = 105381888;  // f32 M    [32][128][256]
constexpr size_t OFF_GATEB = 115867648;  // bf16 gate [4096][2048]
constexpr size_t OFF_WOUTB = 132644864;  // bf16 Wout
constexpr size_t OFF_KC    = 141033472;  // f32 kc
constexpr size_t OFF_VT    = 174587904;  // f32 v transposed [bh*8+vs][t][16]
constexpr size_t OFF_GK    = 208142336;  // f32 log-decay g
constexpr size_t OFF_BETA  = 241696768;  // f32 beta [32][2048]
// total 241958912 bytes (~231 MB), unchanged

// ---------------- small helpers ----------------
__device__ __forceinline__ u16 f2bf(float f) {
  union { float f; u32 u; } a; a.f = f;
  u32 u = a.u;
  u += 0x7fffu + ((u >> 16) & 1u);   // round-to-nearest-even
  return (u16)(u >> 16);
}
__device__ __forceinline__ float bflo(u32 u) {
  union { u32 u; float f; } a; a.u = u << 16; return a.f;
}
__device__ __forceinline__ float bfhi(u32 u) {
  union { u32 u; float f; } a; a.u = u & 0xffff0000u; return a.f;
}
// fast sigmoid: v_exp + v_rcp (~1 ulp each; all consumers round to bf16)
__device__ __forceinline__ float sigmoidf(float x) {
  return __builtin_amdgcn_rcpf(1.0f + __expf(-x));
}
// 16x16x16 bf16 MFMA (HW-verified R5/R7). Layouts: A: row=lane&15,
// k=(lane>>4)*4+i ; B: k=(lane>>4)*4+i, col=lane&15 ; C/D: row=(lane>>4)*4+r,
// col=lane&15.  Used for the state update (K=16 exactly covers s in [0,16);
// the old 16x16x32 ran with k=16..31 all-zero -> identical sum, half the work,
// and the kbs/ush zero tails disappear).
__device__ __forceinline__ f32x4 mfma16b(s4 a, s4 b, f32x4 c) {
  return __builtin_amdgcn_mfma_f32_16x16x16bf16_1k(a, b, c, 0, 0, 0);
}

#define GL_AS1 __attribute__((address_space(1)))
#define GL_AS3 __attribute__((address_space(3)))
__device__ __forceinline__ void async_lds16(const void* g, void* l) {
  __builtin_amdgcn_global_load_lds((GL_AS1 u32*)(size_t)g,
                                   (GL_AS3 u32*)(u32)(size_t)l, 16, 0, 0);
}

// ---------------- fused cast of all f32->bf16 weights/x --------------------
__global__ __launch_bounds__(256) void cast_all(
    const float* __restrict__ x, const float* __restrict__ Wq,
    const float* __restrict__ Wk, const float* __restrict__ Wv,
    const float* __restrict__ Wout, const float* __restrict__ Wf1,
    const float* __restrict__ Wg1, const float* __restrict__ Wf2,
    const float* __restrict__ Wg2,
    u16* __restrict__ xb, u16* __restrict__ wqkv, u16* __restrict__ woutb,
    u16* __restrict__ wf1b, u16* __restrict__ wg1b, u16* __restrict__ wf2b,
    u16* __restrict__ wg2b) {
  long qi = (long)blockIdx.x * 256 + threadIdx.x;   // float4 index
  const float* src; u16* dst; long off;
  if (qi < 2097152)      { src = x;    dst = xb;             off = qi; }
  else if (qi < 3145728) { src = Wq;   dst = wqkv;           off = qi - 2097152; }
  else if (qi < 4194304) { src = Wk;   dst = wqkv + 4194304; off = qi - 3145728; }
  else if (qi < 5242880) { src = Wv;   dst = wqkv + 8388608; off = qi - 4194304; }
  else if (qi < 6291456) { src = Wout; dst = woutb;          off = qi - 5242880; }
  else if (qi < 6356992) { src = Wf1;  dst = wf1b;           off = qi - 6291456; }
  else if (qi < 6422528) { src = Wg1;  dst = wg1b;           off = qi - 6356992; }
  else if (qi < 6488064) { src = Wf2;  dst = wf2b;           off = qi - 6422528; }
  else                   { src = Wg2;  dst = wg2b;           off = qi - 6488064; }
  long i = off * 4;
  float4 v = *(const float4*)(src + i);
  uint2 st;
  st.x = (u32)f2bf(v.x) | ((u32)f2bf(v.y) << 16);
  st.y = (u32)f2bf(v.z) | ((u32)f2bf(v.w) << 16);
  *(uint2*)(dst + i) = st;
}

// Wb [16,2048] f32 -> [128,2048] bf16 zero-padded
__global__ __launch_bounds__(256) void pad_wb(const float* __restrict__ Wb,
                                              u16* __restrict__ out) {
  int i = (blockIdx.x * 256 + threadIdx.x) * 4;  // < 262144
  int row = i >> 11;
  uint2 st; st.x = 0; st.y = 0;
  if (row < 16) {
    float4 v = *(const float4*)(Wb + i);
    st.x = (u32)f2bf(v.x) | ((u32)f2bf(v.y) << 16);
    st.y = (u32)f2bf(v.z) | ((u32)f2bf(v.w) << 16);
  }
  *(uint2*)(out + i) = st;
}

// ---------------- bf16 MFMA GEMM:  C[m,n] = sum_k A[m,k] * B[n,k] ----------
// XCD-aware bijective block swizzle (all launch grids have nwg % 8 == 0):
// consecutive tiles land on the same XCD's L2 -> panel reuse.
template <bool BF16OUT>
__global__ __launch_bounds__(256) void gemm_bt(const u16* __restrict__ A,
                                               const u16* __restrict__ B,
                                               void* __restrict__ Cout,
                                               int lda, int ldb, int ldc, int K) {
  __shared__ u16 As[128 * 32];
  __shared__ u16 Bs[128 * 32];
  const int tid  = threadIdx.x;
  const int lane = tid & 63;
  const int wave = tid >> 6;
  const int wm = (wave >> 1) * 64;
  const int wn = (wave & 1) * 64;
  const int nwg = (int)(gridDim.x * gridDim.y);
  const int lin = (int)(blockIdx.y * gridDim.x + blockIdx.x);
  const int swz = (lin & 7) * (nwg >> 3) + (lin >> 3);
  const long row0 = (long)(swz % (int)gridDim.x) * 128;
  const long col0 = (long)(swz / (int)gridDim.x) * 128;
  const int srow = tid >> 2;
  const int scol = (tid & 3) * 8;
  const u16* aptr = A + (row0 + srow) * (size_t)lda + scol;
  const u16* bptr = B + (col0 + srow) * (size_t)ldb + scol;
  u16* asd  = &As[tid * 8];
  u16* asd2 = &As[2048 + tid * 8];
  u16* bsd  = &Bs[tid * 8];
  u16* bsd2 = &Bs[2048 + tid * 8];
  const int mrow = lane & 15;
  const int kq = (lane >> 4) * 8;
  f32x4 acc[4][4] = {};
  for (int k0 = 0; k0 < K; k0 += 32) {
    async_lds16(aptr, asd);
    async_lds16(aptr + (size_t)64 * lda, asd2);
    async_lds16(bptr, bsd);
    async_lds16(bptr + (size_t)64 * ldb, bsd2);
    aptr += 32; bptr += 32;
    __syncthreads();
    short8 af[4], bfr[4];
#pragma unroll
    for (int i = 0; i < 4; ++i)
      af[i] = *(const short8*)(&As[(wm + i * 16 + mrow) * 32 + kq]);
#pragma unroll
    for (int j = 0; j < 4; ++j)
      bfr[j] = *(const short8*)(&Bs[(wn + j * 16 + mrow) * 32 + kq]);
#pragma unroll
    for (int i = 0; i < 4; ++i)
#pragma unroll
      for (int j = 0; j < 4; ++j)
        acc[i][j] = __builtin_amdgcn_mfma_f32_16x16x32_bf16(af[i], bfr[j], acc[i][j], 0, 0, 0);
    __syncthreads();
  }
  const int cn = lane & 15;
  const int rq = (lane >> 4) * 4;
#pragma unroll
  for (int i = 0; i < 4; ++i)
#pragma unroll
    for (int j = 0; j < 4; ++j) {
      size_t r = (size_t)(row0 + wm + i * 16 + rq);
      size_t c = (size_t)(col0 + wn + j * 16 + cn);
#pragma unroll
      for (int rr = 0; rr < 4; ++rr) {
        if constexpr (BF16OUT)
          ((u16*)Cout)[(r + rr) * ldc + c] = f2bf(acc[i][j][rr]);
        else
          ((float*)Cout)[(r + rr) * ldc + c] = acc[i][j][rr];
      }
    }
}

// ---------------- conv(4-tap causal) + silu + l2norm + g + beta ------------
__global__ __launch_bounds__(256) void convprep(
    const u16* __restrict__ qkv, const u16* __restrict__ graw,
    const u16* __restrict__ fgb,
    const float* __restrict__ qcw, const float* __restrict__ kcw,
    const float* __restrict__ vcw, const float* __restrict__ A_log,
    const float* __restrict__ dt_bias,
    float* __restrict__ qc, float* __restrict__ kc, float* __restrict__ vt,
    float* __restrict__ gdec, float* __restrict__ beta) {
  const int wid = blockIdx.x * 8 + (threadIdx.x >> 5);  // (b*T+t)*H + h
  const int l32 = threadIdx.x & 31;
  const int h  = wid & 15;
  const int bt = wid >> 4;        // b*T + t
  const int t  = bt & (kT - 1);
  const int b  = bt >> 11;
  const int c0 = l32 * 4;
  const size_t colofs = (size_t)h * kK + c0;
  const size_t rowb = (size_t)bt * 6144 + colofs;
  float wqt[4][4], wkt[4][4], wvt[4][4];
#pragma unroll
  for (int j = 0; j < 4; ++j) {
    *(float4*)wqt[j] = *(const float4*)(qcw + (colofs + j) * 4);
    *(float4*)wkt[j] = *(const float4*)(kcw + (colofs + j) * 4);
    *(float4*)wvt[j] = *(const float4*)(vcw + (colofs + j) * 4);
  }
  float qa[4] = {0.f, 0.f, 0.f, 0.f};
  float ka[4] = {0.f, 0.f, 0.f, 0.f};
  float va[4] = {0.f, 0.f, 0.f, 0.f};
#pragma unroll
  for (int i = 0; i < 4; ++i) {
    int tt = t - 3 + i;
    if (tt >= 0) {   // wave-uniform branch
      size_t ro = rowb - (size_t)(3 - i) * 6144;
      uint2 uq = *(const uint2*)(qkv + ro);
      uint2 uk = *(const uint2*)(qkv + ro + 2048);
      uint2 uv = *(const uint2*)(qkv + ro + 4096);
      float q0 = bflo(uq.x), q1 = bfhi(uq.x), q2 = bflo(uq.y), q3 = bfhi(uq.y);
      float k0 = bflo(uk.x), k1 = bfhi(uk.x), k2 = bflo(uk.y), k3 = bfhi(uk.y);
      float v0 = bflo(uv.x), v1 = bfhi(uv.x), v2 = bflo(uv.y), v3 = bfhi(uv.y);
      qa[0] = fmaf(q0, wqt[0][i], qa[0]); qa[1] = fmaf(q1, wqt[1][i], qa[1]);
      qa[2] = fmaf(q2, wqt[2][i], qa[2]); qa[3] = fmaf(q3, wqt[3][i], qa[3]);
      ka[0] = fmaf(k0, wkt[0][i], ka[0]); ka[1] = fmaf(k1, wkt[1][i], ka[1]);
      ka[2] = fmaf(k2, wkt[2][i], ka[2]); ka[3] = fmaf(k3, wkt[3][i], ka[3]);
      va[0] = fmaf(v0, wvt[0][i], va[0]); va[1] = fmaf(v1, wvt[1][i], va[1]);
      va[2] = fmaf(v2, wvt[2][i], va[2]); va[3] = fmaf(v3, wvt[3][i], va[3]);
    }
  }
  float sq = 0.f, sk = 0.f;
#pragma unroll
  for (int j = 0; j < 4; ++j) {
    qa[j] *= sigmoidf(qa[j]);            // silu
    ka[j] *= sigmoidf(ka[j]);
    va[j] *= sigmoidf(va[j]);
    sq = fmaf(qa[j], qa[j], sq);
    sk = fmaf(ka[j], ka[j], sk);
  }
#pragma unroll
  for (int m = 1; m < 32; m <<= 1) {     // reduce within the 32-lane row
    sq += __shfl_xor(sq, m);
    sk += __shfl_xor(sk, m);
  }
  float qinv = __builtin_amdgcn_rcpf(fmaxf(__builtin_amdgcn_sqrtf(sq), 1e-12f));
  float kinv = __builtin_amdgcn_rcpf(fmaxf(__builtin_amdgcn_sqrtf(sk), 1e-12f));
  const int bh = b * kH + h;
  const size_t outb = ((size_t)bh * kT + t) * kK + c0;
  *(float4*)(qc + outb) =
      make_float4(qa[0] * qinv, qa[1] * qinv, qa[2] * qinv, qa[3] * qinv);
  *(float4*)(kc + outb) =
      make_float4(ka[0] * kinv, ka[1] * kinv, ka[2] * kinv, ka[3] * kinv);
  const size_t vtb = ((size_t)(bh * 8 + (c0 >> 4)) * kT + t) * 16 + (c0 & 15);
  *(float4*)(vt + vtb) = make_float4(va[0], va[1], va[2], va[3]);
  uint2 ug = *(const uint2*)(graw + (size_t)bt * kHK + colofs);
  float Ae = __expf(A_log[h]);
  float4 db = *(const float4*)(dt_bias + colofs);
  float g0 = bflo(ug.x) + db.x;
  float g1 = bfhi(ug.x) + db.y;
  float g2 = bflo(ug.y) + db.z;
  float g3 = bfhi(ug.y) + db.w;
  float sp0 = (g0 > 15.f) ? g0 : __logf(1.f + __expf(g0));
  float sp1 = (g1 > 15.f) ? g1 : __logf(1.f + __expf(g1));
  float sp2 = (g2 > 15.f) ? g2 : __logf(1.f + __expf(g2));
  float sp3 = (g3 > 15.f) ? g3 : __logf(1.f + __expf(g3));
  *(float4*)(gdec + outb) = make_float4(-Ae * sp0, -Ae * sp1, -Ae * sp2, -Ae * sp3);
  if (l32 == 0) {
    float bv = bflo((u32)fgb[(size_t)bt * 384 + 256 + h]);
    beta[(size_t)bh * kT + t] = sigmoidf(bv);
  }
}

// ---------------- KDA pass 1: per (bh,chunk) transforms --------------------
// Emits bf16 khat=k*e^G, qhat=q*e^G; kbar=k*e^{GC-G} written TRANSPOSED per
// chunk ([k][16 t]); f32 lam=e^{GC}, Winv=(I+B trilA)^{-1}B and M -- built
// from the ROUNDED khat/qhat/kbar so the chunk algebra is exactly consistent
// with p2's bf16 MFMA operands.  (R2-benched version, verbatim.)
__global__ __launch_bounds__(256) void kda_p1(
    const float* __restrict__ qc, const float* __restrict__ kc,
    const float* __restrict__ gk, const float* __restrict__ betap,
    u16* __restrict__ qhb, u16* __restrict__ khb, u16* __restrict__ kbt,
    float* __restrict__ lamC, float* __restrict__ winv,
    float* __restrict__ mmat) {
  __shared__ float kL[CC][132], qL[CC][132], gL[CC][132];
  __shared__ float As[CC][CC], Ms[CC][CC];
  __shared__ float bet[CC];
  const int tid = threadIdx.x;
  const int bh = blockIdx.x >> 7;
  const int ch = blockIdx.x & 127;
  const size_t base = ((size_t)bh * kT + ch * CC) * kK;
  const int e = tid * 8;
  const int t = e >> 7, k = e & 127;
  {
    *(float4*)&kL[t][k]     = *(const float4*)(kc + base + e);
    *(float4*)&kL[t][k + 4] = *(const float4*)(kc + base + e + 4);
    *(float4*)&qL[t][k]     = *(const float4*)(qc + base + e);
    *(float4*)&qL[t][k + 4] = *(const float4*)(qc + base + e + 4);
    *(float4*)&gL[t][k]     = *(const float4*)(gk + base + e);
    *(float4*)&gL[t][k + 4] = *(const float4*)(gk + base + e + 4);
    if (tid < CC) bet[tid] = betap[(size_t)bh * kT + ch * CC + tid];
  }
  __syncthreads();
  if (tid < kK) {        // inclusive cumsum of g over t -> G
    float a = gL[0][tid];
#pragma unroll
    for (int tt = 1; tt < CC; ++tt) { a += gL[tt][tid]; gL[tt][tid] = a; }
  }
  __syncthreads();
  float khr[8], qhr[8], kbw[8];
  u16 kbv[8];
  u32 pk[4] = {0,0,0,0}, pq[4] = {0,0,0,0};
#pragma unroll
  for (int j = 0; j < 8; ++j) {
    float G  = gL[t][k + j];
    float GC = gL[CC - 1][k + j];
    float eg = __expf(G);
    float kh = kL[t][k + j] * eg;
    float qh = qL[t][k + j] * eg;
    float kb = kL[t][k + j] * __expf(GC - G);
    u16 a = f2bf(kh), b_ = f2bf(qh), c = f2bf(kb);
    pk[j >> 1] |= ((u32)a)  << (16 * (j & 1));
    pq[j >> 1] |= ((u32)b_) << (16 * (j & 1));
    kbv[j] = c;
    khr[j] = bflo((u32)a);
    qhr[j] = bflo((u32)b_);
    kbw[j] = bflo((u32)c) * __expf(-GC);   // kbar * e^{-GC}
  }
  *(uint4*)(khb + base + e) = *(uint4*)pk;
  *(uint4*)(qhb + base + e) = *(uint4*)pq;
  {  // transposed kbar: [bh][ch][k][16 t]; L2 merges the u16 scatter lines
    const size_t kb2 = ((size_t)bh * NCH + ch) * (size_t)(kK * CC) +
                       (size_t)k * CC + t;
#pragma unroll
    for (int j = 0; j < 8; ++j) kbt[kb2 + (size_t)j * CC] = kbv[j];
  }
  if (tid < kK)
    lamC[((size_t)bh * NCH + ch) * kK + tid] = __expf(gL[CC - 1][tid]);
  __syncthreads();   // all GC reads done before overwrite
#pragma unroll
  for (int j = 0; j < 8; ++j) {
    kL[t][k + j] = khr[j];
    qL[t][k + j] = qhr[j];
    gL[t][k + j] = kbw[j];
  }
  __syncthreads();
  {  // A[t][s]=khat_t . (kbar_s e^{-GC}); M[t][s]=qhat_t . (kbar_s e^{-GC})
    const int t2 = tid >> 4, s = tid & 15;
    float av = 0.f, mv = 0.f;
    for (int kk = 0; kk < kK; ++kk) {
      float w = gL[s][kk];
      av = fmaf(kL[t2][kk], w, av);
      mv = fmaf(qL[t2][kk], w, mv);
    }
    As[t2][s] = (s < t2)  ? av : 0.f;
    Ms[t2][s] = (s <= t2) ? mv : 0.f;
  }
  __syncthreads();
  if (tid < CC) {  // X = (I + B trilA)^{-1} B, column s
    const int s = tid;
    float x[CC];
#pragma unroll
    for (int tt = 0; tt < CC; ++tt) {
      float sum = 0.f;
      for (int r = 0; r < tt; ++r) sum += As[tt][r] * x[r];
      x[tt] = ((tt == s) ? bet[tt] : 0.f) - bet[tt] * sum;
    }
    const size_t wb = ((size_t)bh * NCH + ch) * 256;
#pragma unroll
    for (int tt = 0; tt < CC; ++tt) winv[wb + tt * 16 + s] = x[tt];
  }
  mmat[((size_t)bh * NCH + ch) * 256 + tid] = Ms[tid >> 4][tid & 15];
}

// ---------------- KDA pass 2: MFMA chunk recurrence ------------------------
// R2-benched structure (fastest measured: 198 us): 512 blocks = 32 bh x 16
// v-splits(8 cols), 4 waves, 2 blocks/CU. Per chunk:
//   T1 = V - Khat S0 ; U = Winv T1 ; O = Qhat S0 + M U ; S = lam*S0 + Kbar^T U
// Change vs R2: state-update MFMAs use 16x16x16bf16_1k (K=16 == exact s
// range; the old 16x16x32 ran with k=16..31 zero) -> kbs/ush/usl lose their
// zero tails, LDS 65.5 -> 52.7 KB, fewer init/MFMA cycles. Numerics identical.
__global__ __launch_bounds__(256) void kda_p2(
    const u16* __restrict__ khb, const u16* __restrict__ qhb,
    const u16* __restrict__ kbt, const float* __restrict__ lamC,
    const float* __restrict__ winv, const float* __restrict__ mmat,
    const float* __restrict__ vt, float* __restrict__ yf) {
  __shared__ u16 khs[2][CC][136];
  __shared__ u16 qhs[2][CC][136];
  __shared__ u16 kbs[2][kK][20];   // [k][s in 0..15], stride 20 (pad)
  __shared__ float vsx[2][CC][9];
  __shared__ float wsx[2][CC][17];
  __shared__ float msx[2][CC][17];
  __shared__ float lamx[2][kK];
  __shared__ u16 s0h[CC][136];     // S^T bf16-hi [v][k] (rows 8..15 zero)
  __shared__ u16 s0l[CC][136];     // S^T bf16-lo
  __shared__ float pd[4][CC][17];
  __shared__ float qd[4][CC][17];
  __shared__ float t1r[CC][9];
  __shared__ float ufx[CC][9];
  __shared__ u16 ush[CC][20];      // U^T bf16-hi [v][s], rows 8..15 zero
  __shared__ u16 usl[CC][20];
  const int tid = threadIdx.x;
  const int w = tid >> 6, lane = tid & 63;
  const int m15 = lane & 15, q = lane >> 4, q8 = q * 8;
  const int blk = blockIdx.x;
  const int bh = (blk & 7) + ((blk >> 7) << 3);  // same-bh blocks share XCD slot
  const int vs = (blk >> 3) & 15;
  const int cb = vs * 8;
  // zero init (state + the u-transpose zero rows)
  for (int i = tid; i < CC * 136 / 2; i += 256) { ((u32*)s0h)[i] = 0; ((u32*)s0l)[i] = 0; }
  for (int i = tid; i < CC * 20 / 2; i += 256) { ((u32*)ush)[i] = 0; ((u32*)usl)[i] = 0; }

  uint4 rkh, rqh, rkb; float rv, rw, rm, rl;
  auto loadCh = [&](int ch) {
    const size_t cbase = ((size_t)bh * kT + ch * CC) * kK;
    rkh = *(const uint4*)(khb + cbase + tid * 8);
    rqh = *(const uint4*)(qhb + cbase + tid * 8);
    rkb = *(const uint4*)(kbt + ((size_t)bh * NCH + ch) * (size_t)(kK * CC) + tid * 8);
    rv  = (tid < CC * 8)
            ? vt[((size_t)(bh * 8 + (vs >> 1)) * kT + ch * CC + (tid >> 3)) * 16 +
                 (vs & 1) * 8 + (tid & 7)]
            : 0.f;
    const size_t sm = (size_t)bh * NCH + ch;
    rw  = winv[sm * 256 + tid];
    rm  = mmat[sm * 256 + tid];
    rl  = (tid < kK) ? lamC[sm * kK + tid] : 0.f;
  };
  auto writeStage = [&](int b) {
    const int tr = tid >> 4, tc = (tid & 15) * 8;
    *(uint4*)&khs[b][tr][tc] = rkh;
    *(uint4*)&qhs[b][tr][tc] = rqh;
    u16* kd = &kbs[b][tid >> 1][(tid & 1) * 8];   // [k][t] layout, 8B-aligned
    *(uint2*)kd = make_uint2(rkb.x, rkb.y);
    *(uint2*)(kd + 4) = make_uint2(rkb.z, rkb.w);
    if (tid < CC * 8) vsx[b][tid >> 3][tid & 7] = rv;
    wsx[b][tr][tid & 15] = rw;
    msx[b][tr][tid & 15] = rm;
    if (tid < kK) lamx[b][tid] = rl;
  };

  f32x4 St[2] = {};
  loadCh(0);
  for (int ch = 0; ch < NCH; ++ch) {
    const int b = ch & 1;
    writeStage(b);
    if (ch + 1 < NCH) loadCh(ch + 1);
    __syncthreads();  // B1: stage + S0 hi/lo visible
    // phase A: wave-partial K-slice products
    short8 aK = *(const short8*)&khs[b][m15][w * 32 + q8];
    short8 aQ = *(const short8*)&qhs[b][m15][w * 32 + q8];
    short8 sH = *(const short8*)&s0h[m15][w * 32 + q8];
    short8 sL = *(const short8*)&s0l[m15][w * 32 + q8];
    f32x4 z = {0.f, 0.f, 0.f, 0.f};
    f32x4 P  = __builtin_amdgcn_mfma_f32_16x16x32_bf16(aK, sL, z, 0, 0, 0);
    P        = __builtin_amdgcn_mfma_f32_16x16x32_bf16(aK, sH, P, 0, 0, 0);
    f32x4 Qp = __builtin_amdgcn_mfma_f32_16x16x32_bf16(aQ, sL, z, 0, 0, 0);
    Qp       = __builtin_amdgcn_mfma_f32_16x16x32_bf16(aQ, sH, Qp, 0, 0, 0);
#pragma unroll
    for (int r = 0; r < 4; ++r) {
      pd[w][q * 4 + r][m15] = P[r];
      qd[w][q * 4 + r][m15] = Qp[r];
    }
    __syncthreads();  // B2
    const int tt = tid >> 3, vv = tid & 7;   // (t, v) for the 16x8 scalar phases
    float qs = 0.f;
    if (tid < 128) {
      float t1 = vsx[b][tt][vv] -
                 ((pd[0][tt][vv] + pd[1][tt][vv]) + (pd[2][tt][vv] + pd[3][tt][vv]));
      qs = (qd[0][tt][vv] + qd[1][tt][vv]) + (qd[2][tt][vv] + qd[3][tt][vv]);
      t1r[tt][vv] = t1;
    }
    __syncthreads();  // B3
    if (tid < 128) {
      float u = 0.f;
#pragma unroll
      for (int s = 0; s < CC; ++s) u = fmaf(wsx[b][tt][s], t1r[s][vv], u);
      ufx[tt][vv] = u;
      u16 uh = f2bf(u);
      ush[vv][tt] = uh;
      usl[vv][tt] = f2bf(u - bflo(uh));
    }
    __syncthreads();  // B4
    if (tid < 128) {
      float o = qs;
#pragma unroll
      for (int s = 0; s < CC; ++s) o = fmaf(msx[b][tt][s], ufx[s][vv], o);
      yf[((size_t)bh * kT + ch * CC + tt) * kV + cb + vv] = o;
    }
    // state update: S = lam*S + Kbar^T U  (hi/lo _1k mfma pair per tile)
    s4 bH = *(const s4*)&ush[m15][4 * q];
    s4 bL = *(const s4*)&usl[m15][4 * q];
#pragma unroll
    for (int j = 0; j < 2; ++j) {
      const int kt = w * 32 + j * 16;
      f32x4 S = St[j];
#pragma unroll
      for (int r = 0; r < 4; ++r) S[r] *= lamx[b][kt + q * 4 + r];
      s4 aB = *(const s4*)&kbs[b][kt + m15][4 * q];
      S = mfma16b(aB, bL, S);
      S = mfma16b(aB, bH, S);
      St[j] = S;
      u16 h0 = f2bf(S[0]), h1 = f2bf(S[1]), h2 = f2bf(S[2]), h3 = f2bf(S[3]);
      uint2 hw; hw.x = (u32)h0 | ((u32)h1 << 16); hw.y = (u32)h2 | ((u32)h3 << 16);
      *(uint2*)&s0h[m15][kt + q * 4] = hw;
      uint2 lw;
      lw.x = (u32)f2bf(S[0] - bflo(h0)) | ((u32)f2bf(S[1] - bflo(h1)) << 16);
      lw.y = (u32)f2bf(S[2] - bflo(h2)) | ((u32)f2bf(S[3] - bflo(h3)) << 16);
      *(uint2*)&s0l[m15][kt + q * 4] = lw;
    }
  }
}

// ---------------- rmsnorm * o_norm_w * sigmoid(gate+bg) -> bf16 -----------
__global__ __launch_bounds__(256) void postk(
    const float* __restrict__ yf, const u16* __restrict__ gateb,
    const float* __restrict__ bg, const float* __restrict__ onw,
    u16* __restrict__ ygb) {
  const int wid  = blockIdx.x * 4 + (threadIdx.x >> 6);
  const int lane = threadIdx.x & 63;
  const int h  = wid & 15;
  const int bt = wid >> 4;
  const int t  = bt & (kT - 1);
  const int b  = bt >> 11;
  const int v0 = lane * 2;
  const size_t yi = ((size_t)(b * kH + h) * kT + t) * kV + v0;
  float2 yv = *(const float2*)(yf + yi);
  float s = yv.x * yv.x + yv.y * yv.y;
#pragma unroll
  for (int m = 1; m < 64; m <<= 1) s += __shfl_xor(s, m);
  float scale = rsqrtf(s * (1.0f / 128.0f) + 1.1920929e-07f);
  const size_t gi = (size_t)bt * kHV + (size_t)h * kV + v0;
  u32 ug = *(const u32*)(gateb + gi);
  float g0 = bflo(ug) + bg[h * kV + v0];
  float g1 = bfhi(ug) + bg[h * kV + v0 + 1];
  float r0 = yv.x * scale * onw[v0] * sigmoidf(g0);
  float r1 = yv.y * scale * onw[v0 + 1] * sigmoidf(g1);
  *(u32*)(ygb + gi) = (u32)f2bf(r0) | ((u32)f2bf(r1) << 16);
}

// ---------------- host launcher ----------------
extern "C" void kernel_launch(void* const* d_in, const int* in_sizes, int n_in,
                              void* d_out, int out_size, void* d_ws, size_t ws_size,
                              hipStream_t stream) {
  (void)in_sizes; (void)n_in; (void)out_size; (void)ws_size;
  const float* x    = (const float*)d_in[0];
  const float* Wq   = (const float*)d_in[1];
  const float* Wk   = (const float*)d_in[2];
  const float* Wv   = (const float*)d_in[3];
  const float* Wf1  = (const float*)d_in[4];
  const float* Wf2  = (const float*)d_in[5];
  const float* Wb   = (const float*)d_in[6];
  const float* Wg1  = (const float*)d_in[7];
  const float* Wg2  = (const float*)d_in[8];
  const float* bg   = (const float*)d_in[9];
  const float* onw  = (const float*)d_in[10];
  const float* Wout = (const float*)d_in[11];
  const float* A_log   = (const float*)d_in[12];
  const float* dt_bias = (const float*)d_in[13];
  const float* qcw  = (const float*)d_in[14];
  const float* kcw  = (const float*)d_in[15];
  const float* vcw  = (const float*)d_in[16];

  char* ws = (char*)d_ws;
  u16* xb     = (u16*)(ws + OFF_XB);
  u16* wqkv   = (u16*)(ws + OFF_WQKV);
  u16* wf1b   = (u16*)(ws + OFF_WF1B);
  u16* wg1b   = (u16*)(ws + OFF_WG1B);
  u16* wbp    = (u16*)(ws + OFF_WBP);
  u16* wf2b   = (u16*)(ws + OFF_WF2B);
  u16* wg2b   = (u16*)(ws + OFF_WG2B);
  u16* woutb  = (u16*)(ws + OFF_WOUTB);
  u16* fgb    = (u16*)(ws + OFF_FGB);
  u16* qkvraw = (u16*)(ws + OFF_QKVR);
  u16* graw   = (u16*)(ws + OFF_GRAW);
  u16* gateb  = (u16*)(ws + OFF_GATEB);
  u16* qhb    = (u16*)(ws + OFF_QHB);
  u16* khb    = (u16*)(ws + OFF_KHB);
  u16* kbb    = (u16*)(ws + OFF_KBB);
  u16* ygb    = (u16*)(ws + OFF_YGB);
  float* qcf   = (float*)(ws + OFF_QC);
  float* kcf   = (float*)(ws + OFF_KC);
  float* vtf   = (float*)(ws + OFF_VT);
  float* gkf   = (float*)(ws + OFF_GK);
  float* betaf = (float*)(ws + OFF_BETA);
  float* yff   = (float*)(ws + OFF_YF);
  float* lamf  = (float*)(ws + OFF_LAM);
  float* winvf = (float*)(ws + OFF_WINV);
  float* mmf   = (float*)(ws + OFF_MM);

  cast_all<<<25600, 256, 0, stream>>>(x, Wq, Wk, Wv, Wout, Wf1, Wg1, Wf2, Wg2,
                                      xb, wqkv, woutb, wf1b, wg1b, wf2b, wg2b);
  pad_wb<<<(128 * 2048 / 4 + 255) / 256, 256, 0, stream>>>(Wb, wbp);

  dim3 blk(256);
  // qkv: [4096,6144] = x @ [Wq;Wk;Wv]^T
  gemm_bt<true><<<dim3(kM / 128, 6144 / 128), blk, 0, stream>>>(
      xb, wqkv, qkvraw, kD, kD, 6144, kD);
  // fgb: [4096,384] = x @ [Wf1;Wg1;Wbp]^T
  gemm_bt<true><<<dim3(kM / 128, 384 / 128), blk, 0, stream>>>(
      xb, wf1b, fgb, kD, kD, 384, kD);
  // graw: [4096,2048] = f1 @ Wf2^T   (A = fgb cols 0..127, lda 384)
  gemm_bt<true><<<dim3(kM / 128, kHK / 128), blk, 0, stream>>>(
      fgb, wf2b, graw, 384, kV, kHK, kV);
  // gateb: [4096,2048] = g1 @ Wg2^T  (A = fgb cols 128..255)
  gemm_bt<true><<<dim3(kM / 128, kHV / 128), blk, 0, stream>>>(
      fgb + 128, wg2b, gateb, 384, kV, kHV, kV);

  convprep<<<kB * kT * kH / 8, 256, 0, stream>>>(qkvraw, graw, fgb,
                                                 qcw, kcw, vcw, A_log, dt_bias,
                                                 qcf, kcf, vtf, gkf, betaf);

  kda_p1<<<32 * NCH, 256, 0, stream>>>(qcf, kcf, gkf, betaf,
                                       qhb, khb, kbb, lamf, winvf, mmf);
  kda_p2<<<512, 256, 0, stream>>>(khb, qhb, kbb, lamf, winvf, mmf, vtf, yff);

  postk<<<kB * kT * kH / 4, 256, 0, stream>>>(yff, gateb, bg, onw, ygb);

  // out: [4096,2048] = yg @ Wout^T
  gemm_bt<false><<<dim3(kM / 128, kD / 128), blk, 0, stream>>>(
      ygb, woutb, (float*)d_out, kHV, kHV, kD, kHV);
}